// Round 16
// baseline (575.857 us; speedup 1.0000x reference)
//
#include <hip/hip_runtime.h>

#define BB 4
#define TT 2048
#define HH 16
#define ROWS (BB*TT)

typedef unsigned short u16;
typedef __bf16 bf16x8 __attribute__((ext_vector_type(8)));
typedef float f32x4 __attribute__((ext_vector_type(4)));
typedef u16 u16x8 __attribute__((ext_vector_type(8)));
typedef u16 u16x4 __attribute__((ext_vector_type(4)));

__device__ __forceinline__ u16 f2bf(float f) {
  unsigned u = __float_as_uint(f);
  u += 0x7fffu + ((u >> 16) & 1u);
  return (u16)(u >> 16);
}
__device__ __forceinline__ float bf2f(u16 h) {
  return __uint_as_float(((unsigned)h) << 16);
}

__device__ __forceinline__ void gload_lds16(const u16* g, u16* l) {
  __builtin_amdgcn_global_load_lds((const __attribute__((address_space(1))) void*)g,
                                   (__attribute__((address_space(3))) void*)l, 16, 0, 0);
}

// ---------------- fused casts: x + 6 weight segments, one launch ----------------
__global__ __launch_bounds__(256) void cast_all(const float* __restrict__ x,
                                                const float* __restrict__ qdw,
                                                const float* __restrict__ kvdw,
                                                const float* __restrict__ qunw,
                                                const float* __restrict__ qurw,
                                                const float* __restrict__ kvuw,
                                                const float* __restrict__ wow,
                                                u16* __restrict__ xb,
                                                u16* __restrict__ wdc,
                                                u16* __restrict__ wuc,
                                                u16* __restrict__ wkvu,
                                                u16* __restrict__ wwo,
                                                float qsc) {
  const long s0 = 1536L*2048, s1 = 768L*2048, s2 = 2048L*1536,
             s3 = 1024L*1536, s4 = 4096L*512,  s5 = 2048L*2048,
             s6 = (long)ROWS*2048;
  const long total = s0+s1+s2+s3+s4+s5+s6;
  long i = ((long)blockIdx.x * 256 + threadIdx.x) * 4;
  long stride = (long)gridDim.x * 1024;
  for (; i < total; i += stride) {
    long off = i; const float* src; u16* dst; float sc = 1.f; long lim = -1;
    if (off < s0)               { src = qdw;  dst = wdc; }
    else if ((off -= s0) < s1)  { src = kvdw; dst = wdc + s0; lim = 576L*2048; }
    else if ((off -= s1) < s2)  { src = qunw; dst = wuc; sc = qsc; }
    else if ((off -= s2) < s3)  { src = qurw; dst = wuc + s2; }
    else if ((off -= s3) < s4)  { src = kvuw; dst = wkvu; }
    else if ((off -= s4) < s5)  { src = wow;  dst = wwo; }
    else { off -= s5;             src = x;    dst = xb; }
    u16x4 o;
    if (lim < 0 || off + 3 < lim) {
      float4 v = *(const float4*)(src + off);
      o = (u16x4){ f2bf(v.x*sc), f2bf(v.y*sc), f2bf(v.z*sc), f2bf(v.w*sc) };
    } else {
#pragma unroll
      for (int e = 0; e < 4; ++e) o[e] = (off + e < lim) ? f2bf(src[off+e]*sc) : (u16)0;
    }
    *(u16x4*)(dst + off) = o;
  }
}

// ---------------- GEMM A: 256x256, BK=32, 2-deep dbuf + counted vmcnt, 2 blocks/CU ----------------
// Used for down (288 blocks) and q_up (384): both < 512-slot capacity -> single round.
template<int MODE>
__global__ __launch_bounds__(512, 2) void gemm256(const u16* __restrict__ A,
                                                  const u16* __restrict__ Bm,
                                                  void* __restrict__ Cv,
                                                  u16* __restrict__ Vt,
                                                  int M, int N, int K, int lda) {
  __shared__ __align__(16) u16 lds[32768];   // 65536 B
  const int tid = threadIdx.x;
  const int lane = tid & 63, wid = tid >> 6;
  const int wm = (wid >> 2) * 128;
  const int wn = (wid & 3) * 64;

  const int nx = gridDim.x;
  int id = blockIdx.y * nx + blockIdx.x;
  const int cpx = (nx * gridDim.y) >> 3;
  id = (id & 7) * cpx + (id >> 3);
  const int m0 = (id / nx) * 256;
  const int n0 = (id % nx) * 256;

  const int NT = K >> 5;

  f32x4 acc[8][4] = {};

  auto stage = [&](int kt, int d) {
#pragma unroll
    for (int j = 0; j < 2; ++j) {
      int c = j*512 + tid;
      int row = c >> 2;
      int colb = (c & 3) << 4;
      int srcb = colb ^ (((row >> 1) & 3) << 4);
      const u16* ga = (const u16*)((const char*)A + ((long)(m0 + row) * lda + kt*32) * 2 + srcb);
      gload_lds16(ga, (u16*)((char*)lds + d*32768 + c*16));
      const u16* gb = (const u16*)((const char*)Bm + ((long)(n0 + row) * K + kt*32) * 2 + srcb);
      gload_lds16(gb, (u16*)((char*)lds + d*32768 + 16384 + c*16));
    }
  };

  stage(0, 0);
  stage(1, 1);

  const int lr = lane & 15;
  const int kb = (lane >> 4) << 4;

  for (int kt = 0; kt < NT; ++kt) {
    const int cur = kt & 1;
    if (kt + 1 < NT) asm volatile("s_waitcnt vmcnt(4)" ::: "memory");
    else             asm volatile("s_waitcnt vmcnt(0)" ::: "memory");
    __builtin_amdgcn_s_barrier();
    __builtin_amdgcn_sched_barrier(0);

    const char* Ab = (const char*)lds + cur*32768;
    const char* Bb = Ab + 16384;
    bf16x8 af[8], bf[4];
#pragma unroll
    for (int i = 0; i < 8; ++i) {
      int r = wm + i*16 + lr;
      af[i] = *(const bf16x8*)(Ab + r*64 + (kb ^ (((r >> 1) & 3) << 4)));
    }
#pragma unroll
    for (int i = 0; i < 4; ++i) {
      int r = wn + i*16 + lr;
      bf[i] = *(const bf16x8*)(Bb + r*64 + (kb ^ (((r >> 1) & 3) << 4)));
    }
    __builtin_amdgcn_s_setprio(1);
#pragma unroll
    for (int i = 0; i < 8; ++i)
#pragma unroll
      for (int j = 0; j < 4; ++j)
        acc[i][j] = __builtin_amdgcn_mfma_f32_16x16x32_bf16(af[i], bf[j], acc[i][j], 0, 0, 0);
    __builtin_amdgcn_s_setprio(0);
    __builtin_amdgcn_sched_barrier(0);
    __builtin_amdgcn_s_barrier();
    if (kt + 2 < NT) stage(kt + 2, cur);
  }

  const int orow = (lane >> 4) << 2;
  const int ocol = lane & 15;
#pragma unroll
  for (int mf = 0; mf < 8; ++mf)
#pragma unroll
    for (int nf = 0; nf < 4; ++nf) {
      long rbase = (long)(m0 + wm + mf*16 + orow);
      int col = n0 + wn + nf*16 + ocol;
      if (MODE == 0) {
#pragma unroll
        for (int rr = 0; rr < 4; ++rr)
          ((float*)Cv)[(rbase + rr) * (long)N + col] = acc[mf][nf][rr];
      } else if (MODE == 1) {
#pragma unroll
        for (int rr = 0; rr < 4; ++rr)
          ((u16*)Cv)[(rbase + rr) * (long)N + col] = f2bf(acc[mf][nf][rr]);
      } else {
        int h = col >> 8, inner = col & 255;
        if (inner < 128) {
#pragma unroll
          for (int rr = 0; rr < 4; ++rr)
            ((u16*)Cv)[(rbase + rr) * 2048L + h*128 + inner] = f2bf(acc[mf][nf][rr]);
        } else {
          int bb = (int)(rbase >> 11);
          int t  = (int)(rbase & 2047);
          long vo = ((long)(bb*16 + h) * 128 + (inner - 128)) * 2048 + t;
          u16x4 o = { f2bf(acc[mf][nf][0]), f2bf(acc[mf][nf][1]),
                      f2bf(acc[mf][nf][2]), f2bf(acc[mf][nf][3]) };
          *(u16x4*)(Vt + vo) = o;
        }
      }
    }
}

// ---------------- GEMM B: 256x256, BK=64, k-half 4-phase pipeline (T3/T4), 1 block/CU ----------------
// K-tile (64) = 2 k-halves (32). LDS slots (16KB each): A-kh[j][d] @(j*2+d)*16384;
// B-kh[j][d] @65536+(j*2+d)*16384. Tile t -> d=t&1. Per tile: 4 phases (Chalf c x khalf j),
// stage order of tile t+1: A-kh0@p0, B-kh0@p1, A-kh1@p2, B-kh1@p3 (2 loads/thread each).
// Checkpoints: vmcnt(4)+barrier before p0 (retires kh0(t)=oldest 4) and before p2 (retires kh1(t)).
// Steady-state FIFO (8 outstanding at each checkpoint) closes exactly; vmcnt(0) only at final drain.
// WAR: stage at t targets slots last read in t-1 (>=1 checkpoint barrier after all lgkm drains).
// Used for kv_up (512 blocks = 2.0 rounds @1/CU) and wo (256 = 1.0) -- no fractional tail.
template<int MODE>
__global__ __launch_bounds__(512, 2) void gemm256k(const u16* __restrict__ A,
                                                   const u16* __restrict__ Bm,
                                                   void* __restrict__ Cv,
                                                   u16* __restrict__ Vt,
                                                   int M, int N, int K, int lda) {
  __shared__ __align__(16) u16 lds[65536];   // 131072 B
  const int tid = threadIdx.x;
  const int lane = tid & 63, wid = tid >> 6;
  const int wm = (wid >> 2) * 128;
  const int wn = (wid & 3) * 64;

  const int nx = gridDim.x;
  int id = blockIdx.y * nx + blockIdx.x;
  const int cpx = (nx * gridDim.y) >> 3;
  id = (id & 7) * cpx + (id >> 3);
  const int m0 = (id / nx) * 256;
  const int n0 = (id % nx) * 256;

  const int NT = K >> 6;   // BK=64 tiles; NT >= 8 for all uses

  f32x4 acc[8][4] = {};

  // stage one matrix k-half of tile t into its slot (2 gload_lds/thread)
  auto stageH = [&](int mat, int j, int t) {
    const int d = t & 1;
    char* base = (char*)lds + mat*65536 + (j*2 + d)*16384;
    const u16* G = mat ? Bm : A;
    const int r0 = mat ? n0 : m0;
    const long ld = mat ? (long)K : (long)lda;
#pragma unroll
    for (int j2 = 0; j2 < 2; ++j2) {
      int c = j2*512 + tid;                // 16B chunk 0..1023 (1024*16B = 16KB)
      int row = c >> 2;
      int colb = (c & 3) << 4;
      int srcb = colb ^ (((row >> 1) & 3) << 4);
      const u16* g = (const u16*)((const char*)G + ((long)(r0 + row) * ld + t*64 + j*32) * 2 + srcb);
      gload_lds16(g, (u16*)(base + c*16));
    }
  };

  // prologue: tile 0's 4 halves in FIFO order A0,B0,A1,B1 (8 loads/thread)
  stageH(0, 0, 0); stageH(1, 0, 0); stageH(0, 1, 0); stageH(1, 1, 0);

  const int lr = lane & 15;
  const int kb = (lane >> 4) << 4;

  for (int t = 0; t < NT; ++t) {
    const int d = t & 1;
#pragma unroll
    for (int half = 0; half < 2; ++half) {      // consume khalf `half` of tile t
      if (half == 0 || t + 1 < NT) asm volatile("s_waitcnt vmcnt(4)" ::: "memory");
      else                         asm volatile("s_waitcnt vmcnt(0)" ::: "memory");
      __builtin_amdgcn_s_barrier();
      __builtin_amdgcn_sched_barrier(0);

      const char* Ab = (const char*)lds + (half*2 + d)*16384;
      const char* Bb = (const char*)lds + 65536 + (half*2 + d)*16384;
      bf16x8 bf[4];
#pragma unroll
      for (int nb = 0; nb < 4; ++nb) {
        int r = wn + nb*16 + lr;
        bf[nb] = *(const bf16x8*)(Bb + r*64 + (kb ^ (((r >> 1) & 3) << 4)));
      }
#pragma unroll
      for (int c = 0; c < 2; ++c) {             // phase within khalf: C-half c
        bf16x8 af[4];
#pragma unroll
        for (int i = 0; i < 4; ++i) {
          int r = wm + c*64 + i*16 + lr;
          af[i] = *(const bf16x8*)(Ab + r*64 + (kb ^ (((r >> 1) & 3) << 4)));
        }
        if (t + 1 < NT) {
          int pidx = half*2 + c;                // 0..3 -> A0,B0,A1,B1 of tile t+1
          stageH(pidx & 1, pidx >> 1, t + 1);
        }
        __builtin_amdgcn_s_setprio(1);
#pragma unroll
        for (int i = 0; i < 4; ++i)
#pragma unroll
          for (int nb = 0; nb < 4; ++nb)
            acc[c*4 + i][nb] = __builtin_amdgcn_mfma_f32_16x16x32_bf16(af[i], bf[nb], acc[c*4+i][nb], 0, 0, 0);
        __builtin_amdgcn_s_setprio(0);
      }
    }
  }

  const int orow = (lane >> 4) << 2;
  const int ocol = lane & 15;
#pragma unroll
  for (int mf = 0; mf < 8; ++mf)
#pragma unroll
    for (int nf = 0; nf < 4; ++nf) {
      long rbase = (long)(m0 + wm + mf*16 + orow);
      int col = n0 + wn + nf*16 + ocol;
      if (MODE == 0) {
#pragma unroll
        for (int rr = 0; rr < 4; ++rr)
          ((float*)Cv)[(rbase + rr) * (long)N + col] = acc[mf][nf][rr];
      } else if (MODE == 1) {
#pragma unroll
        for (int rr = 0; rr < 4; ++rr)
          ((u16*)Cv)[(rbase + rr) * (long)N + col] = f2bf(acc[mf][nf][rr]);
      } else {
        int h = col >> 8, inner = col & 255;
        if (inner < 128) {
#pragma unroll
          for (int rr = 0; rr < 4; ++rr)
            ((u16*)Cv)[(rbase + rr) * 2048L + h*128 + inner] = f2bf(acc[mf][nf][rr]);
        } else {
          int bb = (int)(rbase >> 11);
          int t2 = (int)(rbase & 2047);
          long vo = ((long)(bb*16 + h) * 128 + (inner - 128)) * 2048 + t2;
          u16x4 o = { f2bf(acc[mf][nf][0]), f2bf(acc[mf][nf][1]),
                      f2bf(acc[mf][nf][2]), f2bf(acc[mf][nf][3]) };
          *(u16x4*)(Vt + vo) = o;
        }
      }
    }
}

// ---------------- fused dual RMSNorm (in-place on dk) + k_rope extraction ----------------
__global__ __launch_bounds__(256) void rms_rope_dk(u16* __restrict__ dk,
                                                   const float* __restrict__ qnw,
                                                   const float* __restrict__ kvnw,
                                                   u16* __restrict__ Kr,
                                                   const float* __restrict__ cosb,
                                                   const float* __restrict__ sinb) {
  const long row = blockIdx.x;
  u16* x = dk + row * 2304;
  const int i = threadIdx.x * 8;
  float sq = 0.f, sk = 0.f;
  u16x8 v = *(const u16x8*)(x + i);
  {
    float s = 0.f;
#pragma unroll
    for (int e = 0; e < 8; ++e) { float f = bf2f(v[e]); s += f*f; }
    if (i < 1536) sq = s; else sk = s;
  }
#pragma unroll
  for (int off = 32; off > 0; off >>= 1) {
    sq += __shfl_down(sq, off);
    sk += __shfl_down(sk, off);
  }
  __shared__ float redq[4], redk[4];
  if ((threadIdx.x & 63) == 0) {
    redq[threadIdx.x >> 6] = sq;
    redk[threadIdx.x >> 6] = sk;
  }
  __syncthreads();
  float rq = rsqrtf((redq[0]+redq[1]+redq[2]+redq[3]) * (1.f/1536.f) + 1e-6f);
  float rk = rsqrtf((redk[0]+redk[1]+redk[2]+redk[3]) * (1.f/512.f) + 1e-6f);
  {
    float r = (i < 1536) ? rq : rk;
    const float* w = (i < 1536) ? (qnw + i) : (kvnw + (i - 1536));
    u16x8 o;
#pragma unroll
    for (int e = 0; e < 8; ++e) o[e] = f2bf(bf2f(v[e]) * r * w[e]);
    *(u16x8*)(x + i) = o;
  }
  if (threadIdx.x < 32) {
    const int t = (int)(row & (TT-1));
    int ii = threadIdx.x;
    float x0 = bf2f(x[2048 + 2*ii]);
    float x1 = bf2f(x[2048 + 2*ii + 1]);
    float c = cosb[t*32 + ii], s = sinb[t*32 + ii];
    Kr[row*64 + 2*ii]     = f2bf(x0*c - x1*s);
    Kr[row*64 + 2*ii + 1] = f2bf(x0*s + x1*c);
  }
}

// ---------------- Flash attention v10: in-register Q-RoPE + static-max softmax + ones-MFMA ----------------
__global__ __launch_bounds__(512) void flash_attn10(const u16* __restrict__ qcat, // [ROWS,3072]
                                                    const u16* __restrict__ kn,   // [ROWS,2048]
                                                    const u16* __restrict__ kr,   // [ROWS,64]
                                                    const u16* __restrict__ Vt,   // [B*H,128,T]
                                                    const float* __restrict__ cosb,
                                                    const float* __restrict__ sinb,
                                                    u16* __restrict__ O) {        // [ROWS,2048]
  __shared__ __align__(16) u16 lds[36864];   // 73728 B
  const int bid = blockIdx.x;
  const int u = bid & 255, sl = bid >> 8;
  const int a = u >> 6;
  const int bh = u & 63;
  const int qt = sl ? a : (7 - a);
  const int b = bh >> 4, h = bh & 15;
  const int wid = threadIdx.x >> 6, lane = threadIdx.x & 63;
  const int q0 = qt*256 + wid*32;
  const long browq = (long)b * TT + q0;
  const long browk = (long)b * TT;
  const int l16 = lane >> 4;
  const int l8  = lane >> 3;
  const int lx16   = (lane & 15) * 16;
  const int lx8_16 = (lane & 7) * 16;
  const int co = l16 * 16;
  const float QSCE = 0.10411754661f;   // (1/sqrt(192)) * log2(e)

  bf16x8 qf[2][6];
#pragma unroll
  for (int f = 0; f < 2; ++f) {
    long row = browq + f*16 + (lane & 15);
#pragma unroll
    for (int ks = 0; ks < 4; ++ks)
      qf[f][ks] = *(const bf16x8*)(qcat + row * 3072 + h*128 + ks*32 + l16 * 8);
    const int t = (int)(row & (TT-1));
#pragma unroll
    for (int ks = 0; ks < 2; ++ks) {
      bf16x8 v = *(const bf16x8*)(qcat + row * 3072 + 2048 + h*64 + ks*32 + l16 * 8);
      const int ib = ks*16 + l16*4;
#pragma unroll
      for (int pp = 0; pp < 4; ++pp) {
        float x0 = (float)v[2*pp], x1 = (float)v[2*pp+1];
        float c = cosb[t*32 + ib + pp], s = sinb[t*32 + ib + pp];
        v[2*pp]   = (__bf16)((x0*c - x1*s) * QSCE);
        v[2*pp+1] = (__bf16)((x0*s + x1*c) * QSCE);
      }
      qf[f][4+ks] = v;
    }
  }

  bf16x8 vones;
#pragma unroll
  for (int e = 0; e < 8; ++e) vones[e] = (__bf16)1.0f;

  f32x4 oacc[2][8] = {};
  f32x4 lsum[2] = {};

  u16* pw = lds + 20480 + wid * 2048;

  const int nIter = 4*qt + 4;
  for (int it = 0; it < nIter; ++it) {
    const int s0 = it * 64;
#pragma unroll
    for (int j = 0; j < 2; ++j) {            // Kn
      int c = j*8 + wid;
      int r = c*4 + l16;
      int cb = lx16 ^ ((r & 7) << 4);
      const u16* src = (const u16*)((const char*)kn + (browk + s0 + r) * 4096 + h * 256 + cb);
      gload_lds16(src, lds + c*512);
    }
    {                                        // Kr
      int c = wid;
      int r = c*8 + l8;
      int cb = lx8_16 ^ ((r & 7) << 4);
      const u16* src = (const u16*)((const char*)kr + (browk + s0 + r) * 128 + cb);
      gload_lds16(src, lds + 8192 + c*512);
    }
#pragma unroll
    for (int j = 0; j < 2; ++j) {            // Vd
      int c = j*8 + wid;
      int d = c*8 + l8;
      int cb = lx8_16 ^ ((d & 7) << 4);
      const u16* src = (const u16*)((const char*)Vt + ((long)bh*128 + d) * (TT*2) + (long)s0*2 + cb);
      gload_lds16(src, lds + 12288 + c*512);
    }
    __syncthreads();

    const bool skip0 = s0 > q0 + 15;
    const bool skip1 = s0 > q0 + 31;
    if (!skip0 || !skip1) {
      __builtin_amdgcn_s_setprio(1);
      f32x4 sacc[2][4] = {};
#pragma unroll
      for (int nt = 0; nt < 4; ++nt) {
        const int r = nt*16 + (lane & 15);
        const int swz = (r & 7) << 4;
        bf16x8 kf[6];
#pragma unroll
        for (int ks = 0; ks < 4; ++ks)
          kf[ks] = *(const bf16x8*)((const char*)lds + r*256 + ((ks*64 + co) ^ swz));
#pragma unroll
        for (int ks = 0; ks < 2; ++ks)
          kf[4+ks] = *(const bf16x8*)((const char*)lds + 16384 + r*128 + ((ks*64 + co) ^ swz));
        if (!skip0) {
#pragma unroll
          for (int ks = 0; ks < 6; ++ks)
            sacc[0][nt] = __builtin_amdgcn_mfma_f32_16x16x32_bf16(qf[0][ks], kf[ks], sacc[0][nt], 0, 0, 0);
        }
        if (!skip1) {
#pragma unroll
          for (int ks = 0; ks < 6; ++ks)
            sacc[1][nt] = __builtin_amdgcn_mfma_f32_16x16x32_bf16(qf[1][ks], kf[ks], sacc[1][nt], 0, 0, 0);
        }
      }
      // static-max softmax: P = exp2(s - 16)
#pragma unroll
      for (int f = 0; f < 2; ++f) {
        const bool skipf = f ? skip1 : skip0;
        if (skipf) continue;
        const int qmin = q0 + f*16;
        const int qb = qmin + (l16 << 2);
        if (s0 + 63 > qmin) {
#pragma unroll
          for (int nt = 0; nt < 4; ++nt) {
            int sc = s0 + nt*16 + (lane & 15);
#pragma unroll
            for (int rr = 0; rr < 4; ++rr)
              if (sc > qb + rr) sacc[f][nt][rr] = -1e30f;
          }
        }
        const int lb2 = (lane & 15) * 2;
#pragma unroll
        for (int rr = 0; rr < 4; ++rr) {
          float p0 = exp2f(sacc[f][0][rr] - 16.f);
          float p1 = exp2f(sacc[f][1][rr] - 16.f);
          float p2 = exp2f(sacc[f][2][rr] - 16.f);
          float p3 = exp2f(sacc[f][3][rr] - 16.f);
          const int prow = f*16 + (l16 << 2) + rr;
          const int sw = (prow & 7) << 4;
          char* pb = (char*)pw + prow*128;
          *(u16*)(pb + ((     lb2) ^ sw)) = f2bf(p0);
          *(u16*)(pb + (( 32 + lb2) ^ sw)) = f2bf(p1);
          *(u16*)(pb + (( 64 + lb2) ^ sw)) = f2bf(p2);
          *(u16*)(pb + (( 96 + lb2) ^ sw)) = f2bf(p3);
        }
      }
      // PV + row-sum via ones-MFMA
#pragma unroll
      for (int ks = 0; ks < 2; ++ks) {
        const int cb = ks*64 + co;
        bf16x8 vf[8];
#pragma unroll
        for (int vt = 0; vt < 8; ++vt) {
          int row = vt*16 + (lane & 15);
          vf[vt] = *(const bf16x8*)((const char*)lds + 24576 + row*128 + (cb ^ ((row & 7) << 4)));
        }
#pragma unroll
        for (int f = 0; f < 2; ++f) {
          if (f ? skip1 : skip0) continue;
          int prow = f*16 + (lane & 15);
          bf16x8 pa = *(const bf16x8*)((const char*)pw + prow*128 + (cb ^ ((prow & 7) << 4)));
          lsum[f] = __builtin_amdgcn_mfma_f32_16x16x32_bf16(pa, vones, lsum[f], 0, 0, 0);
#pragma unroll
          for (int vt = 0; vt < 8; ++vt)
            oacc[f][vt] = __builtin_amdgcn_mfma_f32_16x16x32_bf16(pa, vf[vt], oacc[f][vt], 0, 0, 0);
        }
      }
      __builtin_amdgcn_s_setprio(0);
    }
    __syncthreads();
  }

#pragma unroll
  for (int f = 0; f < 2; ++f) {
    float inv[4];
#pragma unroll
    for (int rr = 0; rr < 4; ++rr) inv[rr] = 1.f / lsum[f][rr];
#pragma unroll
    for (int vt = 0; vt < 8; ++vt)
#pragma unroll
      for (int rr = 0; rr < 4; ++rr) {
        long row = browq + f*16 + (l16 << 2) + rr;
        int col = h*128 + vt*16 + (lane & 15);
        O[row * 2048 + col] = f2bf(oacc[f][vt][rr] * inv[rr]);
      }
  }
}

// ---------------- host ----------------
static inline long minl(long a, long b) { return a < b ? a : b; }

extern "C" void kernel_launch(void* const* d_in, const int* in_sizes, int n_in,
                              void* d_out, int out_size, void* d_ws, size_t ws_size,
                              hipStream_t stream) {
  const float* x    = (const float*)d_in[0];
  const float* fcos = (const float*)d_in[1];
  const float* fsin = (const float*)d_in[2];
  const float* qdw  = (const float*)d_in[4];
  const float* qnw  = (const float*)d_in[5];
  const float* qunw = (const float*)d_in[6];
  const float* qurw = (const float*)d_in[7];
  const float* kvdw = (const float*)d_in[8];
  const float* kvnw = (const float*)d_in[9];
  const float* kvuw = (const float*)d_in[10];
  const float* wow  = (const float*)d_in[11];
  float* out = (float*)d_out;

  char* p = (char*)d_ws;
  auto alloc = [&](size_t bytes) { char* r = p; p += (bytes + 255) & ~(size_t)255; return r; };

  u16* xb   = (u16*)alloc((size_t)ROWS*2048*2);   // x bf16; later Ob
  u16* wdc  = (u16*)alloc((size_t)2304*2048*2);
  u16* wuc  = (u16*)alloc((size_t)3072*1536*2);
  u16* wkvu = (u16*)alloc((size_t)4096*512*2);
  u16* wwo  = (u16*)alloc((size_t)2048*2048*2);
  u16* dk   = (u16*)alloc((size_t)ROWS*2304*2);
  u16* qcat = (u16*)alloc((size_t)ROWS*3072*2);
  u16* kn   = (u16*)alloc((size_t)ROWS*2048*2);
  u16* Vt   = (u16*)alloc((size_t)ROWS*2048*2);
  u16* kro  = (u16*)alloc((size_t)ROWS*64*2);

  u16* Ob = xb;   // xb dead after down GEMM

  const float QSC_E = 0.10411754661f;  // (1/sqrt(192)) * log2(e)

  cast_all<<<4096, 256, 0, stream>>>(x, qdw, kvdw, qunw, qurw, kvuw, wow,
                                     xb, wdc, wuc, wkvu, wwo, QSC_E);

  // down & q_up: BK=32 2-phase (2 blocks/CU, grids < 512 -> single round)
  gemm256<1><<<dim3(9, 32), 512, 0, stream>>>(xb, wdc, dk, nullptr, ROWS, 2304, 2048, 2048);
  rms_rope_dk<<<ROWS, 256, 0, stream>>>(dk, qnw, kvnw, kro, fcos, fsin);
  gemm256<1><<<dim3(12, 32), 512, 0, stream>>>(dk, wuc, qcat, nullptr, ROWS, 3072, 1536, 2304);
  // kv_up & wo: BK=64 k-half pipelined (1 block/CU, grids = exact multiples of 256)
  gemm256k<2><<<dim3(16, 32), 512, 0, stream>>>(dk + 1536, wkvu, kn, Vt, ROWS, 4096, 512, 2304);
  flash_attn10<<<512, 512, 0, stream>>>(qcat, kn, kro, Vt, fcos, fsin, Ob);
  gemm256k<0><<<dim3(8, 32), 512, 0, stream>>>(Ob, wwo, out, nullptr, ROWS, 2048, 2048, 2048);
}

// Round 17
// 538.178 us; speedup vs baseline: 1.0700x; 1.0700x over previous
//
#include <hip/hip_runtime.h>

#define BB 4
#define TT 2048
#define HH 16
#define ROWS (BB*TT)

typedef unsigned short u16;
typedef __bf16 bf16x8 __attribute__((ext_vector_type(8)));
typedef float f32x4 __attribute__((ext_vector_type(4)));
typedef u16 u16x8 __attribute__((ext_vector_type(8)));
typedef u16 u16x4 __attribute__((ext_vector_type(4)));

__device__ __forceinline__ u16 f2bf(float f) {
  unsigned u = __float_as_uint(f);
  u += 0x7fffu + ((u >> 16) & 1u);
  return (u16)(u >> 16);
}
__device__ __forceinline__ float bf2f(u16 h) {
  return __uint_as_float(((unsigned)h) << 16);
}

__device__ __forceinline__ void gload_lds16(const u16* g, u16* l) {
  __builtin_amdgcn_global_load_lds((const __attribute__((address_space(1))) void*)g,
                                   (__attribute__((address_space(3))) void*)l, 16, 0, 0);
}

// ---------------- fused casts: x + 6 weight segments, one launch ----------------
__global__ __launch_bounds__(256) void cast_all(const float* __restrict__ x,
                                                const float* __restrict__ qdw,
                                                const float* __restrict__ kvdw,
                                                const float* __restrict__ qunw,
                                                const float* __restrict__ qurw,
                                                const float* __restrict__ kvuw,
                                                const float* __restrict__ wow,
                                                u16* __restrict__ xb,
                                                u16* __restrict__ wdc,
                                                u16* __restrict__ wuc,
                                                u16* __restrict__ wkvu,
                                                u16* __restrict__ wwo,
                                                float qsc) {
  const long s0 = 1536L*2048, s1 = 768L*2048, s2 = 2048L*1536,
             s3 = 1024L*1536, s4 = 4096L*512,  s5 = 2048L*2048,
             s6 = (long)ROWS*2048;
  const long total = s0+s1+s2+s3+s4+s5+s6;
  long i = ((long)blockIdx.x * 256 + threadIdx.x) * 4;
  long stride = (long)gridDim.x * 1024;
  for (; i < total; i += stride) {
    long off = i; const float* src; u16* dst; float sc = 1.f; long lim = -1;
    if (off < s0)               { src = qdw;  dst = wdc; }
    else if ((off -= s0) < s1)  { src = kvdw; dst = wdc + s0; lim = 576L*2048; }
    else if ((off -= s1) < s2)  { src = qunw; dst = wuc; sc = qsc; }
    else if ((off -= s2) < s3)  { src = qurw; dst = wuc + s2; }
    else if ((off -= s3) < s4)  { src = kvuw; dst = wkvu; }
    else if ((off -= s4) < s5)  { src = wow;  dst = wwo; }
    else { off -= s5;             src = x;    dst = xb; }
    u16x4 o;
    if (lim < 0 || off + 3 < lim) {
      float4 v = *(const float4*)(src + off);
      o = (u16x4){ f2bf(v.x*sc), f2bf(v.y*sc), f2bf(v.z*sc), f2bf(v.w*sc) };
    } else {
#pragma unroll
      for (int e = 0; e < 4; ++e) o[e] = (off + e < lim) ? f2bf(src[off+e]*sc) : (u16)0;
    }
    *(u16x4*)(dst + off) = o;
  }
}

// ---------------- GEMM 256x256, 8 waves, BK=32, 2-deep dbuf + counted vmcnt, 2 blocks/CU ----------------
// LDS 65536 B (buf d at d*32768 B: A[256][32] 16K, B 16K @+16K) -> 2 blocks/CU (16 waves).
// Swizzle for 64-B rows: slot ^= ((row>>1)&3)<<4 (2-way = free); pre-swizzled global source
// (both-sides rule), matching XOR on frag reads. vmcnt(4) counted (never 0 in steady state).
// MODE 0: f32 C. MODE 1: bf16 C. MODE 2 (kv_up): inner<128 -> kn, inner>=128 -> Vt transposed.
template<int MODE>
__global__ __launch_bounds__(512, 2) void gemm256(const u16* __restrict__ A,
                                                  const u16* __restrict__ Bm,
                                                  void* __restrict__ Cv,
                                                  u16* __restrict__ Vt,
                                                  int M, int N, int K, int lda) {
  __shared__ __align__(16) u16 lds[32768];   // 65536 B
  const int tid = threadIdx.x;
  const int lane = tid & 63, wid = tid >> 6;
  const int wm = (wid >> 2) * 128;
  const int wn = (wid & 3) * 64;

  const int nx = gridDim.x;
  int id = blockIdx.y * nx + blockIdx.x;
  const int cpx = (nx * gridDim.y) >> 3;
  id = (id & 7) * cpx + (id >> 3);
  const int m0 = (id / nx) * 256;
  const int n0 = (id % nx) * 256;

  const int NT = K >> 5;   // K-tiles of 32

  f32x4 acc[8][4] = {};

  auto stage = [&](int kt, int d) {
#pragma unroll
    for (int j = 0; j < 2; ++j) {
      int c = j*512 + tid;                 // 16B chunk 0..1023
      int row = c >> 2;
      int colb = (c & 3) << 4;
      int srcb = colb ^ (((row >> 1) & 3) << 4);
      const u16* ga = (const u16*)((const char*)A + ((long)(m0 + row) * lda + kt*32) * 2 + srcb);
      gload_lds16(ga, (u16*)((char*)lds + d*32768 + c*16));
      const u16* gb = (const u16*)((const char*)Bm + ((long)(n0 + row) * K + kt*32) * 2 + srcb);
      gload_lds16(gb, (u16*)((char*)lds + d*32768 + 16384 + c*16));
    }
  };

  stage(0, 0);
  stage(1, 1);

  const int lr = lane & 15;
  const int kb = (lane >> 4) << 4;   // lane's 8-elem slot byte offset: {0,16,32,48}

  for (int kt = 0; kt < NT; ++kt) {
    const int cur = kt & 1;
    if (kt + 1 < NT) asm volatile("s_waitcnt vmcnt(4)" ::: "memory");
    else             asm volatile("s_waitcnt vmcnt(0)" ::: "memory");
    __builtin_amdgcn_s_barrier();
    __builtin_amdgcn_sched_barrier(0);

    const char* Ab = (const char*)lds + cur*32768;
    const char* Bb = Ab + 16384;
    bf16x8 af[8], bf[4];
#pragma unroll
    for (int i = 0; i < 8; ++i) {
      int r = wm + i*16 + lr;
      af[i] = *(const bf16x8*)(Ab + r*64 + (kb ^ (((r >> 1) & 3) << 4)));
    }
#pragma unroll
    for (int i = 0; i < 4; ++i) {
      int r = wn + i*16 + lr;
      bf[i] = *(const bf16x8*)(Bb + r*64 + (kb ^ (((r >> 1) & 3) << 4)));
    }
    __builtin_amdgcn_s_setprio(1);
#pragma unroll
    for (int i = 0; i < 8; ++i)
#pragma unroll
      for (int j = 0; j < 4; ++j)
        acc[i][j] = __builtin_amdgcn_mfma_f32_16x16x32_bf16(af[i], bf[j], acc[i][j], 0, 0, 0);
    __builtin_amdgcn_s_setprio(0);
    __builtin_amdgcn_sched_barrier(0);
    __builtin_amdgcn_s_barrier();          // all waves done reading buf[cur]
    if (kt + 2 < NT) stage(kt + 2, cur);
  }

  const int orow = (lane >> 4) << 2;
  const int ocol = lane & 15;
#pragma unroll
  for (int mf = 0; mf < 8; ++mf)
#pragma unroll
    for (int nf = 0; nf < 4; ++nf) {
      long rbase = (long)(m0 + wm + mf*16 + orow);
      int col = n0 + wn + nf*16 + ocol;
      if (MODE == 0) {
#pragma unroll
        for (int rr = 0; rr < 4; ++rr)
          ((float*)Cv)[(rbase + rr) * (long)N + col] = acc[mf][nf][rr];
      } else if (MODE == 1) {
#pragma unroll
        for (int rr = 0; rr < 4; ++rr)
          ((u16*)Cv)[(rbase + rr) * (long)N + col] = f2bf(acc[mf][nf][rr]);
      } else {
        int h = col >> 8, inner = col & 255;
        if (inner < 128) {
#pragma unroll
          for (int rr = 0; rr < 4; ++rr)
            ((u16*)Cv)[(rbase + rr) * 2048L + h*128 + inner] = f2bf(acc[mf][nf][rr]);
        } else {
          int bb = (int)(rbase >> 11);
          int t  = (int)(rbase & 2047);
          long vo = ((long)(bb*16 + h) * 128 + (inner - 128)) * 2048 + t;
          u16x4 o = { f2bf(acc[mf][nf][0]), f2bf(acc[mf][nf][1]),
                      f2bf(acc[mf][nf][2]), f2bf(acc[mf][nf][3]) };
          *(u16x4*)(Vt + vo) = o;
        }
      }
    }
}

// ---------------- fused dual RMSNorm (in-place on dk) + k_rope extraction ----------------
__global__ __launch_bounds__(256) void rms_rope_dk(u16* __restrict__ dk,
                                                   const float* __restrict__ qnw,
                                                   const float* __restrict__ kvnw,
                                                   u16* __restrict__ Kr,
                                                   const float* __restrict__ cosb,
                                                   const float* __restrict__ sinb) {
  const long row = blockIdx.x;
  u16* x = dk + row * 2304;
  const int i = threadIdx.x * 8;
  float sq = 0.f, sk = 0.f;
  u16x8 v = *(const u16x8*)(x + i);
  {
    float s = 0.f;
#pragma unroll
    for (int e = 0; e < 8; ++e) { float f = bf2f(v[e]); s += f*f; }
    if (i < 1536) sq = s; else sk = s;
  }
#pragma unroll
  for (int off = 32; off > 0; off >>= 1) {
    sq += __shfl_down(sq, off);
    sk += __shfl_down(sk, off);
  }
  __shared__ float redq[4], redk[4];
  if ((threadIdx.x & 63) == 0) {
    redq[threadIdx.x >> 6] = sq;
    redk[threadIdx.x >> 6] = sk;
  }
  __syncthreads();
  float rq = rsqrtf((redq[0]+redq[1]+redq[2]+redq[3]) * (1.f/1536.f) + 1e-6f);
  float rk = rsqrtf((redk[0]+redk[1]+redk[2]+redk[3]) * (1.f/512.f) + 1e-6f);
  {
    float r = (i < 1536) ? rq : rk;
    const float* w = (i < 1536) ? (qnw + i) : (kvnw + (i - 1536));
    u16x8 o;
#pragma unroll
    for (int e = 0; e < 8; ++e) o[e] = f2bf(bf2f(v[e]) * r * w[e]);
    *(u16x8*)(x + i) = o;
  }
  if (threadIdx.x < 32) {
    const int t = (int)(row & (TT-1));
    int ii = threadIdx.x;
    float x0 = bf2f(x[2048 + 2*ii]);
    float x1 = bf2f(x[2048 + 2*ii + 1]);
    float c = cosb[t*32 + ii], s = sinb[t*32 + ii];
    Kr[row*64 + 2*ii]     = f2bf(x0*c - x1*s);
    Kr[row*64 + 2*ii + 1] = f2bf(x0*s + x1*c);
  }
}

// ---------------- Flash attention v10: in-register Q-RoPE + static-max softmax + ones-MFMA ----------------
// LDS bytes: Kn [64][256B] @0; Kr [64][128B] @16384; Vd [128][128B] @24576;
// P [32][128B]/wave @40960 + wid*4096. Total 73728 B. __launch_bounds__(512) REQUIRED (VGPR 128).
__global__ __launch_bounds__(512) void flash_attn10(const u16* __restrict__ qcat, // [ROWS,3072]
                                                    const u16* __restrict__ kn,   // [ROWS,2048]
                                                    const u16* __restrict__ kr,   // [ROWS,64]
                                                    const u16* __restrict__ Vt,   // [B*H,128,T]
                                                    const float* __restrict__ cosb,
                                                    const float* __restrict__ sinb,
                                                    u16* __restrict__ O) {        // [ROWS,2048]
  __shared__ __align__(16) u16 lds[36864];   // 73728 B
  const int bid = blockIdx.x;
  const int u = bid & 255, sl = bid >> 8;
  const int a = u >> 6;
  const int bh = u & 63;
  const int qt = sl ? a : (7 - a);
  const int b = bh >> 4, h = bh & 15;
  const int wid = threadIdx.x >> 6, lane = threadIdx.x & 63;
  const int q0 = qt*256 + wid*32;
  const long browq = (long)b * TT + q0;
  const long browk = (long)b * TT;
  const int l16 = lane >> 4;
  const int l8  = lane >> 3;
  const int lx16   = (lane & 15) * 16;
  const int lx8_16 = (lane & 7) * 16;
  const int co = l16 * 16;
  const float QSCE = 0.10411754661f;   // (1/sqrt(192)) * log2(e)

  bf16x8 qf[2][6];
#pragma unroll
  for (int f = 0; f < 2; ++f) {
    long row = browq + f*16 + (lane & 15);
#pragma unroll
    for (int ks = 0; ks < 4; ++ks)
      qf[f][ks] = *(const bf16x8*)(qcat + row * 3072 + h*128 + ks*32 + l16 * 8);
    const int t = (int)(row & (TT-1));
#pragma unroll
    for (int ks = 0; ks < 2; ++ks) {
      bf16x8 v = *(const bf16x8*)(qcat + row * 3072 + 2048 + h*64 + ks*32 + l16 * 8);
      const int ib = ks*16 + l16*4;
#pragma unroll
      for (int pp = 0; pp < 4; ++pp) {
        float x0 = (float)v[2*pp], x1 = (float)v[2*pp+1];
        float c = cosb[t*32 + ib + pp], s = sinb[t*32 + ib + pp];
        v[2*pp]   = (__bf16)((x0*c - x1*s) * QSCE);
        v[2*pp+1] = (__bf16)((x0*s + x1*c) * QSCE);
      }
      qf[f][4+ks] = v;
    }
  }

  bf16x8 vones;
#pragma unroll
  for (int e = 0; e < 8; ++e) vones[e] = (__bf16)1.0f;

  f32x4 oacc[2][8] = {};
  f32x4 lsum[2] = {};

  u16* pw = lds + 20480 + wid * 2048;

  const int nIter = 4*qt + 4;
  for (int it = 0; it < nIter; ++it) {
    const int s0 = it * 64;
#pragma unroll
    for (int j = 0; j < 2; ++j) {            // Kn
      int c = j*8 + wid;
      int r = c*4 + l16;
      int cb = lx16 ^ ((r & 7) << 4);
      const u16* src = (const u16*)((const char*)kn + (browk + s0 + r) * 4096 + h * 256 + cb);
      gload_lds16(src, lds + c*512);
    }
    {                                        // Kr
      int c = wid;
      int r = c*8 + l8;
      int cb = lx8_16 ^ ((r & 7) << 4);
      const u16* src = (const u16*)((const char*)kr + (browk + s0 + r) * 128 + cb);
      gload_lds16(src, lds + 8192 + c*512);
    }
#pragma unroll
    for (int j = 0; j < 2; ++j) {            // Vd
      int c = j*8 + wid;
      int d = c*8 + l8;
      int cb = lx8_16 ^ ((d & 7) << 4);
      const u16* src = (const u16*)((const char*)Vt + ((long)bh*128 + d) * (TT*2) + (long)s0*2 + cb);
      gload_lds16(src, lds + 12288 + c*512);
    }
    __syncthreads();

    const bool skip0 = s0 > q0 + 15;
    const bool skip1 = s0 > q0 + 31;
    if (!skip0 || !skip1) {
      __builtin_amdgcn_s_setprio(1);
      f32x4 sacc[2][4] = {};
#pragma unroll
      for (int nt = 0; nt < 4; ++nt) {
        const int r = nt*16 + (lane & 15);
        const int swz = (r & 7) << 4;
        bf16x8 kf[6];
#pragma unroll
        for (int ks = 0; ks < 4; ++ks)
          kf[ks] = *(const bf16x8*)((const char*)lds + r*256 + ((ks*64 + co) ^ swz));
#pragma unroll
        for (int ks = 0; ks < 2; ++ks)
          kf[4+ks] = *(const bf16x8*)((const char*)lds + 16384 + r*128 + ((ks*64 + co) ^ swz));
        if (!skip0) {
#pragma unroll
          for (int ks = 0; ks < 6; ++ks)
            sacc[0][nt] = __builtin_amdgcn_mfma_f32_16x16x32_bf16(qf[0][ks], kf[ks], sacc[0][nt], 0, 0, 0);
        }
        if (!skip1) {
#pragma unroll
          for (int ks = 0; ks < 6; ++ks)
            sacc[1][nt] = __builtin_amdgcn_mfma_f32_16x16x32_bf16(qf[1][ks], kf[ks], sacc[1][nt], 0, 0, 0);
        }
      }
      // static-max softmax: P = exp2(s - 16)
#pragma unroll
      for (int f = 0; f < 2; ++f) {
        const bool skipf = f ? skip1 : skip0;
        if (skipf) continue;
        const int qmin = q0 + f*16;
        const int qb = qmin + (l16 << 2);
        if (s0 + 63 > qmin) {
#pragma unroll
          for (int nt = 0; nt < 4; ++nt) {
            int sc = s0 + nt*16 + (lane & 15);
#pragma unroll
            for (int rr = 0; rr < 4; ++rr)
              if (sc > qb + rr) sacc[f][nt][rr] = -1e30f;
          }
        }
        const int lb2 = (lane & 15) * 2;
#pragma unroll
        for (int rr = 0; rr < 4; ++rr) {
          float p0 = exp2f(sacc[f][0][rr] - 16.f);
          float p1 = exp2f(sacc[f][1][rr] - 16.f);
          float p2 = exp2f(sacc[f][2][rr] - 16.f);
          float p3 = exp2f(sacc[f][3][rr] - 16.f);
          const int prow = f*16 + (l16 << 2) + rr;
          const int sw = (prow & 7) << 4;
          char* pb = (char*)pw + prow*128;
          *(u16*)(pb + ((     lb2) ^ sw)) = f2bf(p0);
          *(u16*)(pb + (( 32 + lb2) ^ sw)) = f2bf(p1);
          *(u16*)(pb + (( 64 + lb2) ^ sw)) = f2bf(p2);
          *(u16*)(pb + (( 96 + lb2) ^ sw)) = f2bf(p3);
        }
      }
      // PV + row-sum via ones-MFMA
#pragma unroll
      for (int ks = 0; ks < 2; ++ks) {
        const int cb = ks*64 + co;
        bf16x8 vf[8];
#pragma unroll
        for (int vt = 0; vt < 8; ++vt) {
          int row = vt*16 + (lane & 15);
          vf[vt] = *(const bf16x8*)((const char*)lds + 24576 + row*128 + (cb ^ ((row & 7) << 4)));
        }
#pragma unroll
        for (int f = 0; f < 2; ++f) {
          if (f ? skip1 : skip0) continue;
          int prow = f*16 + (lane & 15);
          bf16x8 pa = *(const bf16x8*)((const char*)pw + prow*128 + (cb ^ ((prow & 7) << 4)));
          lsum[f] = __builtin_amdgcn_mfma_f32_16x16x32_bf16(pa, vones, lsum[f], 0, 0, 0);
#pragma unroll
          for (int vt = 0; vt < 8; ++vt)
            oacc[f][vt] = __builtin_amdgcn_mfma_f32_16x16x32_bf16(pa, vf[vt], oacc[f][vt], 0, 0, 0);
        }
      }
      __builtin_amdgcn_s_setprio(0);
    }
    __syncthreads();
  }

#pragma unroll
  for (int f = 0; f < 2; ++f) {
    float inv[4];
#pragma unroll
    for (int rr = 0; rr < 4; ++rr) inv[rr] = 1.f / lsum[f][rr];
#pragma unroll
    for (int vt = 0; vt < 8; ++vt)
#pragma unroll
      for (int rr = 0; rr < 4; ++rr) {
        long row = browq + f*16 + (l16 << 2) + rr;
        int col = h*128 + vt*16 + (lane & 15);
        O[row * 2048 + col] = f2bf(oacc[f][vt][rr] * inv[rr]);
      }
  }
}

// ---------------- host ----------------
static inline long minl(long a, long b) { return a < b ? a : b; }

extern "C" void kernel_launch(void* const* d_in, const int* in_sizes, int n_in,
                              void* d_out, int out_size, void* d_ws, size_t ws_size,
                              hipStream_t stream) {
  const float* x    = (const float*)d_in[0];
  const float* fcos = (const float*)d_in[1];
  const float* fsin = (const float*)d_in[2];
  const float* qdw  = (const float*)d_in[4];
  const float* qnw  = (const float*)d_in[5];
  const float* qunw = (const float*)d_in[6];
  const float* qurw = (const float*)d_in[7];
  const float* kvdw = (const float*)d_in[8];
  const float* kvnw = (const float*)d_in[9];
  const float* kvuw = (const float*)d_in[10];
  const float* wow  = (const float*)d_in[11];
  float* out = (float*)d_out;

  char* p = (char*)d_ws;
  auto alloc = [&](size_t bytes) { char* r = p; p += (bytes + 255) & ~(size_t)255; return r; };

  u16* xb   = (u16*)alloc((size_t)ROWS*2048*2);   // x bf16; later Ob
  u16* wdc  = (u16*)alloc((size_t)2304*2048*2);
  u16* wuc  = (u16*)alloc((size_t)3072*1536*2);
  u16* wkvu = (u16*)alloc((size_t)4096*512*2);
  u16* wwo  = (u16*)alloc((size_t)2048*2048*2);
  u16* dk   = (u16*)alloc((size_t)ROWS*2304*2);
  u16* qcat = (u16*)alloc((size_t)ROWS*3072*2);
  u16* kn   = (u16*)alloc((size_t)ROWS*2048*2);
  u16* Vt   = (u16*)alloc((size_t)ROWS*2048*2);
  u16* kro  = (u16*)alloc((size_t)ROWS*64*2);

  u16* Ob = xb;   // xb dead after down GEMM

  const float QSC_E = 0.10411754661f;  // (1/sqrt(192)) * log2(e)

  cast_all<<<4096, 256, 0, stream>>>(x, qdw, kvdw, qunw, qurw, kvuw, wow,
                                     xb, wdc, wuc, wkvu, wwo, QSC_E);

  gemm256<1><<<dim3(9, 32), 512, 0, stream>>>(xb, wdc, dk, nullptr, ROWS, 2304, 2048, 2048);
  rms_rope_dk<<<ROWS, 256, 0, stream>>>(dk, qnw, kvnw, kro, fcos, fsin);
  gemm256<1><<<dim3(12, 32), 512, 0, stream>>>(dk, wuc, qcat, nullptr, ROWS, 3072, 1536, 2304);
  gemm256<2><<<dim3(16, 32), 512, 0, stream>>>(dk + 1536, wkvu, kn, Vt, ROWS, 4096, 512, 2304);
  flash_attn10<<<512, 512, 0, stream>>>(qcat, kn, kro, Vt, fcos, fsin, Ob);
  gemm256<0><<<dim3(8, 32), 512, 0, stream>>>(Ob, wwo, out, nullptr, ROWS, 2048, 2048, 2048);
}

// Round 18
// 515.844 us; speedup vs baseline: 1.1163x; 1.0433x over previous
//
#include <hip/hip_runtime.h>

#define BB 4
#define TT 2048
#define HH 16
#define ROWS (BB*TT)

typedef unsigned short u16;
typedef __bf16 bf16x8 __attribute__((ext_vector_type(8)));
typedef float f32x4 __attribute__((ext_vector_type(4)));
typedef u16 u16x8 __attribute__((ext_vector_type(8)));
typedef u16 u16x4 __attribute__((ext_vector_type(4)));

__device__ __forceinline__ u16 f2bf(float f) {
  unsigned u = __float_as_uint(f);
  u += 0x7fffu + ((u >> 16) & 1u);
  return (u16)(u >> 16);
}
__device__ __forceinline__ float bf2f(u16 h) {
  return __uint_as_float(((unsigned)h) << 16);
}

__device__ __forceinline__ void gload_lds16(const u16* g, u16* l) {
  __builtin_amdgcn_global_load_lds((const __attribute__((address_space(1))) void*)g,
                                   (__attribute__((address_space(3))) void*)l, 16, 0, 0);
}

// ---------------- fused casts: x + 6 weight segments, one launch ----------------
__global__ __launch_bounds__(256) void cast_all(const float* __restrict__ x,
                                                const float* __restrict__ qdw,
                                                const float* __restrict__ kvdw,
                                                const float* __restrict__ qunw,
                                                const float* __restrict__ qurw,
                                                const float* __restrict__ kvuw,
                                                const float* __restrict__ wow,
                                                u16* __restrict__ xb,
                                                u16* __restrict__ wdc,
                                                u16* __restrict__ wuc,
                                                u16* __restrict__ wkvu,
                                                u16* __restrict__ wwo,
                                                float qsc) {
  const long s0 = 1536L*2048, s1 = 768L*2048, s2 = 2048L*1536,
             s3 = 1024L*1536, s4 = 4096L*512,  s5 = 2048L*2048,
             s6 = (long)ROWS*2048;
  const long total = s0+s1+s2+s3+s4+s5+s6;
  long i = ((long)blockIdx.x * 256 + threadIdx.x) * 4;
  long stride = (long)gridDim.x * 1024;
  for (; i < total; i += stride) {
    long off = i; const float* src; u16* dst; float sc = 1.f; long lim = -1;
    if (off < s0)               { src = qdw;  dst = wdc; }
    else if ((off -= s0) < s1)  { src = kvdw; dst = wdc + s0; lim = 576L*2048; }
    else if ((off -= s1) < s2)  { src = qunw; dst = wuc; sc = qsc; }
    else if ((off -= s2) < s3)  { src = qurw; dst = wuc + s2; }
    else if ((off -= s3) < s4)  { src = kvuw; dst = wkvu; }
    else if ((off -= s4) < s5)  { src = wow;  dst = wwo; }
    else { off -= s5;             src = x;    dst = xb; }
    u16x4 o;
    if (lim < 0 || off + 3 < lim) {
      float4 v = *(const float4*)(src + off);
      o = (u16x4){ f2bf(v.x*sc), f2bf(v.y*sc), f2bf(v.z*sc), f2bf(v.w*sc) };
    } else {
#pragma unroll
      for (int e = 0; e < 4; ++e) o[e] = (off + e < lim) ? f2bf(src[off+e]*sc) : (u16)0;
    }
    *(u16x4*)(dst + off) = o;
  }
}

// ---------------- GEMM core macro-body (BK=32, 2-deep dbuf, counted vmcnt, 2 blocks/CU) ----------------
// Shared by gemm256 (single GEMM) and gemm_up (fused q_up+kv_up). Epilogue differs.

// ---------------- GEMM 256x256 single: used for down (MODE 1) and wo (MODE 0) ----------------
template<int MODE>
__global__ __launch_bounds__(512, 2) void gemm256(const u16* __restrict__ A,
                                                  const u16* __restrict__ Bm,
                                                  void* __restrict__ Cv,
                                                  int M, int N, int K, int lda) {
  __shared__ __align__(16) u16 lds[32768];   // 65536 B
  const int tid = threadIdx.x;
  const int lane = tid & 63, wid = tid >> 6;
  const int wm = (wid >> 2) * 128;
  const int wn = (wid & 3) * 64;

  const int nx = gridDim.x;
  int id = blockIdx.y * nx + blockIdx.x;
  const int cpx = (nx * gridDim.y) >> 3;
  id = (id & 7) * cpx + (id >> 3);
  const int m0 = (id / nx) * 256;
  const int n0 = (id % nx) * 256;

  const int NT = K >> 5;

  f32x4 acc[8][4] = {};

  auto stage = [&](int kt, int d) {
#pragma unroll
    for (int j = 0; j < 2; ++j) {
      int c = j*512 + tid;
      int row = c >> 2;
      int colb = (c & 3) << 4;
      int srcb = colb ^ (((row >> 1) & 3) << 4);
      const u16* ga = (const u16*)((const char*)A + ((long)(m0 + row) * lda + kt*32) * 2 + srcb);
      gload_lds16(ga, (u16*)((char*)lds + d*32768 + c*16));
      const u16* gb = (const u16*)((const char*)Bm + ((long)(n0 + row) * K + kt*32) * 2 + srcb);
      gload_lds16(gb, (u16*)((char*)lds + d*32768 + 16384 + c*16));
    }
  };

  stage(0, 0);
  stage(1, 1);

  const int lr = lane & 15;
  const int kb = (lane >> 4) << 4;

  for (int kt = 0; kt < NT; ++kt) {
    const int cur = kt & 1;
    if (kt + 1 < NT) asm volatile("s_waitcnt vmcnt(4)" ::: "memory");
    else             asm volatile("s_waitcnt vmcnt(0)" ::: "memory");
    __builtin_amdgcn_s_barrier();
    __builtin_amdgcn_sched_barrier(0);

    const char* Ab = (const char*)lds + cur*32768;
    const char* Bb = Ab + 16384;
    bf16x8 af[8], bf[4];
#pragma unroll
    for (int i = 0; i < 8; ++i) {
      int r = wm + i*16 + lr;
      af[i] = *(const bf16x8*)(Ab + r*64 + (kb ^ (((r >> 1) & 3) << 4)));
    }
#pragma unroll
    for (int i = 0; i < 4; ++i) {
      int r = wn + i*16 + lr;
      bf[i] = *(const bf16x8*)(Bb + r*64 + (kb ^ (((r >> 1) & 3) << 4)));
    }
    __builtin_amdgcn_s_setprio(1);
#pragma unroll
    for (int i = 0; i < 8; ++i)
#pragma unroll
      for (int j = 0; j < 4; ++j)
        acc[i][j] = __builtin_amdgcn_mfma_f32_16x16x32_bf16(af[i], bf[j], acc[i][j], 0, 0, 0);
    __builtin_amdgcn_s_setprio(0);
    __builtin_amdgcn_sched_barrier(0);
    __builtin_amdgcn_s_barrier();
    if (kt + 2 < NT) stage(kt + 2, cur);
  }

  const int orow = (lane >> 4) << 2;
  const int ocol = lane & 15;
#pragma unroll
  for (int mf = 0; mf < 8; ++mf)
#pragma unroll
    for (int nf = 0; nf < 4; ++nf) {
      long rbase = (long)(m0 + wm + mf*16 + orow);
      int col = n0 + wn + nf*16 + ocol;
      if (MODE == 0) {
#pragma unroll
        for (int rr = 0; rr < 4; ++rr)
          ((float*)Cv)[(rbase + rr) * (long)N + col] = acc[mf][nf][rr];
      } else {
#pragma unroll
        for (int rr = 0; rr < 4; ++rr)
          ((u16*)Cv)[(rbase + rr) * (long)N + col] = f2bf(acc[mf][nf][rr]);
      }
    }
}

// ---------------- fused up-projection: q_up (384 blocks) + kv_up (512 blocks) in one launch ----------------
// blocks 0..383: qcat = dk[:, :1536] @ wuc^T (N=3072). blocks 384..895: kv_up with split
// epilogue (kn + Vt-transposed). Heavy q_up blocks dispatch first (longest-first); kv_up
// backfills the 128 idle slots q_up leaves. Per-segment bijective XCD swizzle (384,512 % 8 == 0).
__global__ __launch_bounds__(512, 2) void gemm_up(const u16* __restrict__ dk,
                                                  const u16* __restrict__ wuc,
                                                  const u16* __restrict__ wkvu,
                                                  u16* __restrict__ qcat,
                                                  u16* __restrict__ kn,
                                                  u16* __restrict__ Vt) {
  __shared__ __align__(16) u16 lds[32768];   // 65536 B
  const int tid = threadIdx.x;
  const int lane = tid & 63, wid = tid >> 6;
  const int wm = (wid >> 2) * 128;
  const int wn = (wid & 3) * 64;

  const int bid = blockIdx.x;
  const bool isQ = bid < 384;
  int lid = isQ ? bid : bid - 384;
  const int nwg = isQ ? 384 : 512;
  const int nx  = isQ ? 12 : 16;
  const int cpx = nwg >> 3;
  lid = (lid & 7) * cpx + (lid >> 3);
  const int m0 = (lid / nx) * 256;
  const int n0 = (lid % nx) * 256;

  const u16* A  = isQ ? dk : (dk + 1536);
  const u16* Bm = isQ ? wuc : wkvu;
  const int K   = isQ ? 1536 : 512;
  const int lda = 2304;
  const int NT  = K >> 5;

  f32x4 acc[8][4] = {};

  auto stage = [&](int kt, int d) {
#pragma unroll
    for (int j = 0; j < 2; ++j) {
      int c = j*512 + tid;
      int row = c >> 2;
      int colb = (c & 3) << 4;
      int srcb = colb ^ (((row >> 1) & 3) << 4);
      const u16* ga = (const u16*)((const char*)A + ((long)(m0 + row) * lda + kt*32) * 2 + srcb);
      gload_lds16(ga, (u16*)((char*)lds + d*32768 + c*16));
      const u16* gb = (const u16*)((const char*)Bm + ((long)(n0 + row) * K + kt*32) * 2 + srcb);
      gload_lds16(gb, (u16*)((char*)lds + d*32768 + 16384 + c*16));
    }
  };

  stage(0, 0);
  stage(1, 1);

  const int lr = lane & 15;
  const int kb = (lane >> 4) << 4;

  for (int kt = 0; kt < NT; ++kt) {
    const int cur = kt & 1;
    if (kt + 1 < NT) asm volatile("s_waitcnt vmcnt(4)" ::: "memory");
    else             asm volatile("s_waitcnt vmcnt(0)" ::: "memory");
    __builtin_amdgcn_s_barrier();
    __builtin_amdgcn_sched_barrier(0);

    const char* Ab = (const char*)lds + cur*32768;
    const char* Bb = Ab + 16384;
    bf16x8 af[8], bf[4];
#pragma unroll
    for (int i = 0; i < 8; ++i) {
      int r = wm + i*16 + lr;
      af[i] = *(const bf16x8*)(Ab + r*64 + (kb ^ (((r >> 1) & 3) << 4)));
    }
#pragma unroll
    for (int i = 0; i < 4; ++i) {
      int r = wn + i*16 + lr;
      bf[i] = *(const bf16x8*)(Bb + r*64 + (kb ^ (((r >> 1) & 3) << 4)));
    }
    __builtin_amdgcn_s_setprio(1);
#pragma unroll
    for (int i = 0; i < 8; ++i)
#pragma unroll
      for (int j = 0; j < 4; ++j)
        acc[i][j] = __builtin_amdgcn_mfma_f32_16x16x32_bf16(af[i], bf[j], acc[i][j], 0, 0, 0);
    __builtin_amdgcn_s_setprio(0);
    __builtin_amdgcn_sched_barrier(0);
    __builtin_amdgcn_s_barrier();
    if (kt + 2 < NT) stage(kt + 2, cur);
  }

  const int orow = (lane >> 4) << 2;
  const int ocol = lane & 15;
#pragma unroll
  for (int mf = 0; mf < 8; ++mf)
#pragma unroll
    for (int nf = 0; nf < 4; ++nf) {
      long rbase = (long)(m0 + wm + mf*16 + orow);
      int col = n0 + wn + nf*16 + ocol;
      if (isQ) {
#pragma unroll
        for (int rr = 0; rr < 4; ++rr)
          qcat[(rbase + rr) * 3072L + col] = f2bf(acc[mf][nf][rr]);
      } else {
        int h = col >> 8, inner = col & 255;
        if (inner < 128) {
#pragma unroll
          for (int rr = 0; rr < 4; ++rr)
            kn[(rbase + rr) * 2048L + h*128 + inner] = f2bf(acc[mf][nf][rr]);
        } else {
          int bb = (int)(rbase >> 11);
          int t  = (int)(rbase & 2047);
          long vo = ((long)(bb*16 + h) * 128 + (inner - 128)) * 2048 + t;
          u16x4 o = { f2bf(acc[mf][nf][0]), f2bf(acc[mf][nf][1]),
                      f2bf(acc[mf][nf][2]), f2bf(acc[mf][nf][3]) };
          *(u16x4*)(Vt + vo) = o;
        }
      }
    }
}

// ---------------- fused dual RMSNorm (in-place on dk) + k_rope extraction ----------------
__global__ __launch_bounds__(256) void rms_rope_dk(u16* __restrict__ dk,
                                                   const float* __restrict__ qnw,
                                                   const float* __restrict__ kvnw,
                                                   u16* __restrict__ Kr,
                                                   const float* __restrict__ cosb,
                                                   const float* __restrict__ sinb) {
  const long row = blockIdx.x;
  u16* x = dk + row * 2304;
  const int i = threadIdx.x * 8;
  float sq = 0.f, sk = 0.f;
  u16x8 v = *(const u16x8*)(x + i);
  {
    float s = 0.f;
#pragma unroll
    for (int e = 0; e < 8; ++e) { float f = bf2f(v[e]); s += f*f; }
    if (i < 1536) sq = s; else sk = s;
  }
#pragma unroll
  for (int off = 32; off > 0; off >>= 1) {
    sq += __shfl_down(sq, off);
    sk += __shfl_down(sk, off);
  }
  __shared__ float redq[4], redk[4];
  if ((threadIdx.x & 63) == 0) {
    redq[threadIdx.x >> 6] = sq;
    redk[threadIdx.x >> 6] = sk;
  }
  __syncthreads();
  float rq = rsqrtf((redq[0]+redq[1]+redq[2]+redq[3]) * (1.f/1536.f) + 1e-6f);
  float rk = rsqrtf((redk[0]+redk[1]+redk[2]+redk[3]) * (1.f/512.f) + 1e-6f);
  {
    float r = (i < 1536) ? rq : rk;
    const float* w = (i < 1536) ? (qnw + i) : (kvnw + (i - 1536));
    u16x8 o;
#pragma unroll
    for (int e = 0; e < 8; ++e) o[e] = f2bf(bf2f(v[e]) * r * w[e]);
    *(u16x8*)(x + i) = o;
  }
  if (threadIdx.x < 32) {
    const int t = (int)(row & (TT-1));
    int ii = threadIdx.x;
    float x0 = bf2f(x[2048 + 2*ii]);
    float x1 = bf2f(x[2048 + 2*ii + 1]);
    float c = cosb[t*32 + ii], s = sinb[t*32 + ii];
    Kr[row*64 + 2*ii]     = f2bf(x0*c - x1*s);
    Kr[row*64 + 2*ii + 1] = f2bf(x0*s + x1*c);
  }
}

// ---------------- Flash attention v10: in-register Q-RoPE + static-max softmax + ones-MFMA ----------------
__global__ __launch_bounds__(512) void flash_attn10(const u16* __restrict__ qcat, // [ROWS,3072]
                                                    const u16* __restrict__ kn,   // [ROWS,2048]
                                                    const u16* __restrict__ kr,   // [ROWS,64]
                                                    const u16* __restrict__ Vt,   // [B*H,128,T]
                                                    const float* __restrict__ cosb,
                                                    const float* __restrict__ sinb,
                                                    u16* __restrict__ O) {        // [ROWS,2048]
  __shared__ __align__(16) u16 lds[36864];   // 73728 B
  const int bid = blockIdx.x;
  const int u = bid & 255, sl = bid >> 8;
  const int a = u >> 6;
  const int bh = u & 63;
  const int qt = sl ? a : (7 - a);
  const int b = bh >> 4, h = bh & 15;
  const int wid = threadIdx.x >> 6, lane = threadIdx.x & 63;
  const int q0 = qt*256 + wid*32;
  const long browq = (long)b * TT + q0;
  const long browk = (long)b * TT;
  const int l16 = lane >> 4;
  const int l8  = lane >> 3;
  const int lx16   = (lane & 15) * 16;
  const int lx8_16 = (lane & 7) * 16;
  const int co = l16 * 16;
  const float QSCE = 0.10411754661f;   // (1/sqrt(192)) * log2(e)

  bf16x8 qf[2][6];
#pragma unroll
  for (int f = 0; f < 2; ++f) {
    long row = browq + f*16 + (lane & 15);
#pragma unroll
    for (int ks = 0; ks < 4; ++ks)
      qf[f][ks] = *(const bf16x8*)(qcat + row * 3072 + h*128 + ks*32 + l16 * 8);
    const int t = (int)(row & (TT-1));
#pragma unroll
    for (int ks = 0; ks < 2; ++ks) {
      bf16x8 v = *(const bf16x8*)(qcat + row * 3072 + 2048 + h*64 + ks*32 + l16 * 8);
      const int ib = ks*16 + l16*4;
#pragma unroll
      for (int pp = 0; pp < 4; ++pp) {
        float x0 = (float)v[2*pp], x1 = (float)v[2*pp+1];
        float c = cosb[t*32 + ib + pp], s = sinb[t*32 + ib + pp];
        v[2*pp]   = (__bf16)((x0*c - x1*s) * QSCE);
        v[2*pp+1] = (__bf16)((x0*s + x1*c) * QSCE);
      }
      qf[f][4+ks] = v;
    }
  }

  bf16x8 vones;
#pragma unroll
  for (int e = 0; e < 8; ++e) vones[e] = (__bf16)1.0f;

  f32x4 oacc[2][8] = {};
  f32x4 lsum[2] = {};

  u16* pw = lds + 20480 + wid * 2048;

  const int nIter = 4*qt + 4;
  for (int it = 0; it < nIter; ++it) {
    const int s0 = it * 64;
#pragma unroll
    for (int j = 0; j < 2; ++j) {            // Kn
      int c = j*8 + wid;
      int r = c*4 + l16;
      int cb = lx16 ^ ((r & 7) << 4);
      const u16* src = (const u16*)((const char*)kn + (browk + s0 + r) * 4096 + h * 256 + cb);
      gload_lds16(src, lds + c*512);
    }
    {                                        // Kr
      int c = wid;
      int r = c*8 + l8;
      int cb = lx8_16 ^ ((r & 7) << 4);
      const u16* src = (const u16*)((const char*)kr + (browk + s0 + r) * 128 + cb);
      gload_lds16(src, lds + 8192 + c*512);
    }
#pragma unroll
    for (int j = 0; j < 2; ++j) {            // Vd
      int c = j*8 + wid;
      int d = c*8 + l8;
      int cb = lx8_16 ^ ((d & 7) << 4);
      const u16* src = (const u16*)((const char*)Vt + ((long)bh*128 + d) * (TT*2) + (long)s0*2 + cb);
      gload_lds16(src, lds + 12288 + c*512);
    }
    __syncthreads();

    const bool skip0 = s0 > q0 + 15;
    const bool skip1 = s0 > q0 + 31;
    if (!skip0 || !skip1) {
      __builtin_amdgcn_s_setprio(1);
      f32x4 sacc[2][4] = {};
#pragma unroll
      for (int nt = 0; nt < 4; ++nt) {
        const int r = nt*16 + (lane & 15);
        const int swz = (r & 7) << 4;
        bf16x8 kf[6];
#pragma unroll
        for (int ks = 0; ks < 4; ++ks)
          kf[ks] = *(const bf16x8*)((const char*)lds + r*256 + ((ks*64 + co) ^ swz));
#pragma unroll
        for (int ks = 0; ks < 2; ++ks)
          kf[4+ks] = *(const bf16x8*)((const char*)lds + 16384 + r*128 + ((ks*64 + co) ^ swz));
        if (!skip0) {
#pragma unroll
          for (int ks = 0; ks < 6; ++ks)
            sacc[0][nt] = __builtin_amdgcn_mfma_f32_16x16x32_bf16(qf[0][ks], kf[ks], sacc[0][nt], 0, 0, 0);
        }
        if (!skip1) {
#pragma unroll
          for (int ks = 0; ks < 6; ++ks)
            sacc[1][nt] = __builtin_amdgcn_mfma_f32_16x16x32_bf16(qf[1][ks], kf[ks], sacc[1][nt], 0, 0, 0);
        }
      }
      // static-max softmax: P = exp2(s - 16)
#pragma unroll
      for (int f = 0; f < 2; ++f) {
        const bool skipf = f ? skip1 : skip0;
        if (skipf) continue;
        const int qmin = q0 + f*16;
        const int qb = qmin + (l16 << 2);
        if (s0 + 63 > qmin) {
#pragma unroll
          for (int nt = 0; nt < 4; ++nt) {
            int sc = s0 + nt*16 + (lane & 15);
#pragma unroll
            for (int rr = 0; rr < 4; ++rr)
              if (sc > qb + rr) sacc[f][nt][rr] = -1e30f;
          }
        }
        const int lb2 = (lane & 15) * 2;
#pragma unroll
        for (int rr = 0; rr < 4; ++rr) {
          float p0 = exp2f(sacc[f][0][rr] - 16.f);
          float p1 = exp2f(sacc[f][1][rr] - 16.f);
          float p2 = exp2f(sacc[f][2][rr] - 16.f);
          float p3 = exp2f(sacc[f][3][rr] - 16.f);
          const int prow = f*16 + (l16 << 2) + rr;
          const int sw = (prow & 7) << 4;
          char* pb = (char*)pw + prow*128;
          *(u16*)(pb + ((     lb2) ^ sw)) = f2bf(p0);
          *(u16*)(pb + (( 32 + lb2) ^ sw)) = f2bf(p1);
          *(u16*)(pb + (( 64 + lb2) ^ sw)) = f2bf(p2);
          *(u16*)(pb + (( 96 + lb2) ^ sw)) = f2bf(p3);
        }
      }
      // PV + row-sum via ones-MFMA
#pragma unroll
      for (int ks = 0; ks < 2; ++ks) {
        const int cb = ks*64 + co;
        bf16x8 vf[8];
#pragma unroll
        for (int vt = 0; vt < 8; ++vt) {
          int row = vt*16 + (lane & 15);
          vf[vt] = *(const bf16x8*)((const char*)lds + 24576 + row*128 + (cb ^ ((row & 7) << 4)));
        }
#pragma unroll
        for (int f = 0; f < 2; ++f) {
          if (f ? skip1 : skip0) continue;
          int prow = f*16 + (lane & 15);
          bf16x8 pa = *(const bf16x8*)((const char*)pw + prow*128 + (cb ^ ((prow & 7) << 4)));
          lsum[f] = __builtin_amdgcn_mfma_f32_16x16x32_bf16(pa, vones, lsum[f], 0, 0, 0);
#pragma unroll
          for (int vt = 0; vt < 8; ++vt)
            oacc[f][vt] = __builtin_amdgcn_mfma_f32_16x16x32_bf16(pa, vf[vt], oacc[f][vt], 0, 0, 0);
        }
      }
      __builtin_amdgcn_s_setprio(0);
    }
    __syncthreads();
  }

#pragma unroll
  for (int f = 0; f < 2; ++f) {
    float inv[4];
#pragma unroll
    for (int rr = 0; rr < 4; ++rr) inv[rr] = 1.f / lsum[f][rr];
#pragma unroll
    for (int vt = 0; vt < 8; ++vt)
#pragma unroll
      for (int rr = 0; rr < 4; ++rr) {
        long row = browq + f*16 + (l16 << 2) + rr;
        int col = h*128 + vt*16 + (lane & 15);
        O[row * 2048 + col] = f2bf(oacc[f][vt][rr] * inv[rr]);
      }
  }
}

// ---------------- host ----------------
static inline long minl(long a, long b) { return a < b ? a : b; }

extern "C" void kernel_launch(void* const* d_in, const int* in_sizes, int n_in,
                              void* d_out, int out_size, void* d_ws, size_t ws_size,
                              hipStream_t stream) {
  const float* x    = (const float*)d_in[0];
  const float* fcos = (const float*)d_in[1];
  const float* fsin = (const float*)d_in[2];
  const float* qdw  = (const float*)d_in[4];
  const float* qnw  = (const float*)d_in[5];
  const float* qunw = (const float*)d_in[6];
  const float* qurw = (const float*)d_in[7];
  const float* kvdw = (const float*)d_in[8];
  const float* kvnw = (const float*)d_in[9];
  const float* kvuw = (const float*)d_in[10];
  const float* wow  = (const float*)d_in[11];
  float* out = (float*)d_out;

  char* p = (char*)d_ws;
  auto alloc = [&](size_t bytes) { char* r = p; p += (bytes + 255) & ~(size_t)255; return r; };

  u16* xb   = (u16*)alloc((size_t)ROWS*2048*2);   // x bf16; later Ob
  u16* wdc  = (u16*)alloc((size_t)2304*2048*2);
  u16* wuc  = (u16*)alloc((size_t)3072*1536*2);
  u16* wkvu = (u16*)alloc((size_t)4096*512*2);
  u16* wwo  = (u16*)alloc((size_t)2048*2048*2);
  u16* dk   = (u16*)alloc((size_t)ROWS*2304*2);
  u16* qcat = (u16*)alloc((size_t)ROWS*3072*2);
  u16* kn   = (u16*)alloc((size_t)ROWS*2048*2);
  u16* Vt   = (u16*)alloc((size_t)ROWS*2048*2);
  u16* kro  = (u16*)alloc((size_t)ROWS*64*2);

  u16* Ob = xb;   // xb dead after down GEMM

  const float QSC_E = 0.10411754661f;  // (1/sqrt(192)) * log2(e)

  cast_all<<<4096, 256, 0, stream>>>(x, qdw, kvdw, qunw, qurw, kvuw, wow,
                                     xb, wdc, wuc, wkvu, wwo, QSC_E);

  gemm256<1><<<dim3(9, 32), 512, 0, stream>>>(xb, wdc, dk, ROWS, 2304, 2048, 2048);
  rms_rope_dk<<<ROWS, 256, 0, stream>>>(dk, qnw, kvnw, kro, fcos, fsin);
  // fused q_up + kv_up (896 blocks; q_up first = longest-first)
  gemm_up<<<896, 512, 0, stream>>>(dk, wuc, wkvu, qcat, kn, Vt);
  flash_attn10<<<512, 512, 0, stream>>>(qcat, kn, kro, Vt, fcos, fsin, Ob);
  gemm256<0><<<dim3(8, 32), 512, 0, stream>>>(Ob, wwo, out, ROWS, 2048, 2048, 2048);
}

// Round 19
// 501.475 us; speedup vs baseline: 1.1483x; 1.0287x over previous
//
#include <hip/hip_runtime.h>

#define BB 4
#define TT 2048
#define HH 16
#define ROWS (BB*TT)

typedef unsigned short u16;
typedef __bf16 bf16x8 __attribute__((ext_vector_type(8)));
typedef float f32x4 __attribute__((ext_vector_type(4)));
typedef u16 u16x8 __attribute__((ext_vector_type(8)));
typedef u16 u16x4 __attribute__((ext_vector_type(4)));

__device__ __forceinline__ u16 f2bf(float f) {
  unsigned u = __float_as_uint(f);
  u += 0x7fffu + ((u >> 16) & 1u);
  return (u16)(u >> 16);
}
__device__ __forceinline__ float bf2f(u16 h) {
  return __uint_as_float(((unsigned)h) << 16);
}

__device__ __forceinline__ void gload_lds16(const u16* g, u16* l) {
  __builtin_amdgcn_global_load_lds((const __attribute__((address_space(1))) void*)g,
                                   (__attribute__((address_space(3))) void*)l, 16, 0, 0);
}

// ---------------- fused casts: x + 6 weight segments, one launch ----------------
__global__ __launch_bounds__(256) void cast_all(const float* __restrict__ x,
                                                const float* __restrict__ qdw,
                                                const float* __restrict__ kvdw,
                                                const float* __restrict__ qunw,
                                                const float* __restrict__ qurw,
                                                const float* __restrict__ kvuw,
                                                const float* __restrict__ wow,
                                                u16* __restrict__ xb,
                                                u16* __restrict__ wdc,
                                                u16* __restrict__ wuc,
                                                u16* __restrict__ wkvu,
                                                u16* __restrict__ wwo,
                                                float qsc) {
  const long s0 = 1536L*2048, s1 = 768L*2048, s2 = 2048L*1536,
             s3 = 1024L*1536, s4 = 4096L*512,  s5 = 2048L*2048,
             s6 = (long)ROWS*2048;
  const long total = s0+s1+s2+s3+s4+s5+s6;
  long i = ((long)blockIdx.x * 256 + threadIdx.x) * 4;
  long stride = (long)gridDim.x * 1024;
  for (; i < total; i += stride) {
    long off = i; const float* src; u16* dst; float sc = 1.f; long lim = -1;
    if (off < s0)               { src = qdw;  dst = wdc; }
    else if ((off -= s0) < s1)  { src = kvdw; dst = wdc + s0; lim = 576L*2048; }
    else if ((off -= s1) < s2)  { src = qunw; dst = wuc; sc = qsc; }
    else if ((off -= s2) < s3)  { src = qurw; dst = wuc + s2; }
    else if ((off -= s3) < s4)  { src = kvuw; dst = wkvu; }
    else if ((off -= s4) < s5)  { src = wow;  dst = wwo; }
    else { off -= s5;             src = x;    dst = xb; }
    u16x4 o;
    if (lim < 0 || off + 3 < lim) {
      float4 v = *(const float4*)(src + off);
      o = (u16x4){ f2bf(v.x*sc), f2bf(v.y*sc), f2bf(v.z*sc), f2bf(v.w*sc) };
    } else {
#pragma unroll
      for (int e = 0; e < 4; ++e) o[e] = (off + e < lim) ? f2bf(src[off+e]*sc) : (u16)0;
    }
    *(u16x4*)(dst + off) = o;
  }
}

// ---------------- GEMM 256x256 single (BK=32, 2-deep dbuf + counted vmcnt) ----------------
// MODE 0: f32 C (wo). MODE 1: bf16 C.
template<int MODE>
__global__ __launch_bounds__(512, 2) void gemm256(const u16* __restrict__ A,
                                                  const u16* __restrict__ Bm,
                                                  void* __restrict__ Cv,
                                                  int M, int N, int K, int lda) {
  __shared__ __align__(16) u16 lds[32768];   // 65536 B
  const int tid = threadIdx.x;
  const int lane = tid & 63, wid = tid >> 6;
  const int wm = (wid >> 2) * 128;
  const int wn = (wid & 3) * 64;

  const int nx = gridDim.x;
  int id = blockIdx.y * nx + blockIdx.x;
  const int cpx = (nx * gridDim.y) >> 3;
  id = (id & 7) * cpx + (id >> 3);
  const int m0 = (id / nx) * 256;
  const int n0 = (id % nx) * 256;

  const int NT = K >> 5;

  f32x4 acc[8][4] = {};

  auto stage = [&](int kt, int d) {
#pragma unroll
    for (int j = 0; j < 2; ++j) {
      int c = j*512 + tid;
      int row = c >> 2;
      int colb = (c & 3) << 4;
      int srcb = colb ^ (((row >> 1) & 3) << 4);
      const u16* ga = (const u16*)((const char*)A + ((long)(m0 + row) * lda + kt*32) * 2 + srcb);
      gload_lds16(ga, (u16*)((char*)lds + d*32768 + c*16));
      const u16* gb = (const u16*)((const char*)Bm + ((long)(n0 + row) * K + kt*32) * 2 + srcb);
      gload_lds16(gb, (u16*)((char*)lds + d*32768 + 16384 + c*16));
    }
  };

  stage(0, 0);
  stage(1, 1);

  const int lr = lane & 15;
  const int kb = (lane >> 4) << 4;

  for (int kt = 0; kt < NT; ++kt) {
    const int cur = kt & 1;
    if (kt + 1 < NT) asm volatile("s_waitcnt vmcnt(4)" ::: "memory");
    else             asm volatile("s_waitcnt vmcnt(0)" ::: "memory");
    __builtin_amdgcn_s_barrier();
    __builtin_amdgcn_sched_barrier(0);

    const char* Ab = (const char*)lds + cur*32768;
    const char* Bb = Ab + 16384;
    bf16x8 af[8], bf[4];
#pragma unroll
    for (int i = 0; i < 8; ++i) {
      int r = wm + i*16 + lr;
      af[i] = *(const bf16x8*)(Ab + r*64 + (kb ^ (((r >> 1) & 3) << 4)));
    }
#pragma unroll
    for (int i = 0; i < 4; ++i) {
      int r = wn + i*16 + lr;
      bf[i] = *(const bf16x8*)(Bb + r*64 + (kb ^ (((r >> 1) & 3) << 4)));
    }
    __builtin_amdgcn_s_setprio(1);
#pragma unroll
    for (int i = 0; i < 8; ++i)
#pragma unroll
      for (int j = 0; j < 4; ++j)
        acc[i][j] = __builtin_amdgcn_mfma_f32_16x16x32_bf16(af[i], bf[j], acc[i][j], 0, 0, 0);
    __builtin_amdgcn_s_setprio(0);
    __builtin_amdgcn_sched_barrier(0);
    __builtin_amdgcn_s_barrier();
    if (kt + 2 < NT) stage(kt + 2, cur);
  }

  const int orow = (lane >> 4) << 2;
  const int ocol = lane & 15;
#pragma unroll
  for (int mf = 0; mf < 8; ++mf)
#pragma unroll
    for (int nf = 0; nf < 4; ++nf) {
      long rbase = (long)(m0 + wm + mf*16 + orow);
      int col = n0 + wn + nf*16 + ocol;
      if (MODE == 0) {
#pragma unroll
        for (int rr = 0; rr < 4; ++rr)
          ((float*)Cv)[(rbase + rr) * (long)N + col] = acc[mf][nf][rr];
      } else {
#pragma unroll
        for (int rr = 0; rr < 4; ++rr)
          ((u16*)Cv)[(rbase + rr) * (long)N + col] = f2bf(acc[mf][nf][rr]);
      }
    }
}

// ---------------- down GEMM, K-split x2: 576 blocks (256^2 tile, K=1024 each) ----------------
// grid dim3(9,64): after bijective XCD swizzle, r=id/9 in [0,64): mtile=r>>1, kpart=r&1.
// kpart 0 -> dkA, kpart 1 -> dkB (partial sums, added in rms_rope_dk). Fixes the 288-block
// tail quantization (2.0 rounds -> 1.5 rounds of half-duration blocks).
__global__ __launch_bounds__(512, 2) void gemm_down(const u16* __restrict__ A,
                                                    const u16* __restrict__ Bm,
                                                    u16* __restrict__ dkA,
                                                    u16* __restrict__ dkB) {
  __shared__ __align__(16) u16 lds[32768];   // 65536 B
  const int tid = threadIdx.x;
  const int lane = tid & 63, wid = tid >> 6;
  const int wm = (wid >> 2) * 128;
  const int wn = (wid & 3) * 64;

  int id = blockIdx.y * 9 + blockIdx.x;      // 0..575
  id = (id & 7) * 72 + (id >> 3);            // bijective (576 % 8 == 0)
  const int rrow = id / 9;
  const int n0 = (id % 9) * 256;
  const int m0 = (rrow >> 1) * 256;
  const int kpart = rrow & 1;
  const int k0 = kpart * 1024;
  u16* Cv = kpart ? dkB : dkA;
  const int NT = 32;                         // 1024 / 32

  f32x4 acc[8][4] = {};

  auto stage = [&](int kt, int d) {
#pragma unroll
    for (int j = 0; j < 2; ++j) {
      int c = j*512 + tid;
      int row = c >> 2;
      int colb = (c & 3) << 4;
      int srcb = colb ^ (((row >> 1) & 3) << 4);
      const u16* ga = (const u16*)((const char*)A + ((long)(m0 + row) * 2048 + k0 + kt*32) * 2 + srcb);
      gload_lds16(ga, (u16*)((char*)lds + d*32768 + c*16));
      const u16* gb = (const u16*)((const char*)Bm + ((long)(n0 + row) * 2048 + k0 + kt*32) * 2 + srcb);
      gload_lds16(gb, (u16*)((char*)lds + d*32768 + 16384 + c*16));
    }
  };

  stage(0, 0);
  stage(1, 1);

  const int lr = lane & 15;
  const int kb = (lane >> 4) << 4;

  for (int kt = 0; kt < NT; ++kt) {
    const int cur = kt & 1;
    if (kt + 1 < NT) asm volatile("s_waitcnt vmcnt(4)" ::: "memory");
    else             asm volatile("s_waitcnt vmcnt(0)" ::: "memory");
    __builtin_amdgcn_s_barrier();
    __builtin_amdgcn_sched_barrier(0);

    const char* Ab = (const char*)lds + cur*32768;
    const char* Bb = Ab + 16384;
    bf16x8 af[8], bf[4];
#pragma unroll
    for (int i = 0; i < 8; ++i) {
      int r = wm + i*16 + lr;
      af[i] = *(const bf16x8*)(Ab + r*64 + (kb ^ (((r >> 1) & 3) << 4)));
    }
#pragma unroll
    for (int i = 0; i < 4; ++i) {
      int r = wn + i*16 + lr;
      bf[i] = *(const bf16x8*)(Bb + r*64 + (kb ^ (((r >> 1) & 3) << 4)));
    }
    __builtin_amdgcn_s_setprio(1);
#pragma unroll
    for (int i = 0; i < 8; ++i)
#pragma unroll
      for (int j = 0; j < 4; ++j)
        acc[i][j] = __builtin_amdgcn_mfma_f32_16x16x32_bf16(af[i], bf[j], acc[i][j], 0, 0, 0);
    __builtin_amdgcn_s_setprio(0);
    __builtin_amdgcn_sched_barrier(0);
    __builtin_amdgcn_s_barrier();
    if (kt + 2 < NT) stage(kt + 2, cur);
  }

  const int orow = (lane >> 4) << 2;
  const int ocol = lane & 15;
#pragma unroll
  for (int mf = 0; mf < 8; ++mf)
#pragma unroll
    for (int nf = 0; nf < 4; ++nf) {
      long rbase = (long)(m0 + wm + mf*16 + orow);
      int col = n0 + wn + nf*16 + ocol;
#pragma unroll
      for (int rr = 0; rr < 4; ++rr)
        Cv[(rbase + rr) * 2304L + col] = f2bf(acc[mf][nf][rr]);
    }
}

// ---------------- fused up-projection: q_up (384 blocks) + kv_up (512 blocks) in one launch ----------------
__global__ __launch_bounds__(512, 2) void gemm_up(const u16* __restrict__ dk,
                                                  const u16* __restrict__ wuc,
                                                  const u16* __restrict__ wkvu,
                                                  u16* __restrict__ qcat,
                                                  u16* __restrict__ kn,
                                                  u16* __restrict__ Vt) {
  __shared__ __align__(16) u16 lds[32768];   // 65536 B
  const int tid = threadIdx.x;
  const int lane = tid & 63, wid = tid >> 6;
  const int wm = (wid >> 2) * 128;
  const int wn = (wid & 3) * 64;

  const int bid = blockIdx.x;
  const bool isQ = bid < 384;
  int lid = isQ ? bid : bid - 384;
  const int nwg = isQ ? 384 : 512;
  const int nx  = isQ ? 12 : 16;
  const int cpx = nwg >> 3;
  lid = (lid & 7) * cpx + (lid >> 3);
  const int m0 = (lid / nx) * 256;
  const int n0 = (lid % nx) * 256;

  const u16* A  = isQ ? dk : (dk + 1536);
  const u16* Bm = isQ ? wuc : wkvu;
  const int K   = isQ ? 1536 : 512;
  const int lda = 2304;
  const int NT  = K >> 5;

  f32x4 acc[8][4] = {};

  auto stage = [&](int kt, int d) {
#pragma unroll
    for (int j = 0; j < 2; ++j) {
      int c = j*512 + tid;
      int row = c >> 2;
      int colb = (c & 3) << 4;
      int srcb = colb ^ (((row >> 1) & 3) << 4);
      const u16* ga = (const u16*)((const char*)A + ((long)(m0 + row) * lda + kt*32) * 2 + srcb);
      gload_lds16(ga, (u16*)((char*)lds + d*32768 + c*16));
      const u16* gb = (const u16*)((const char*)Bm + ((long)(n0 + row) * K + kt*32) * 2 + srcb);
      gload_lds16(gb, (u16*)((char*)lds + d*32768 + 16384 + c*16));
    }
  };

  stage(0, 0);
  stage(1, 1);

  const int lr = lane & 15;
  const int kb = (lane >> 4) << 4;

  for (int kt = 0; kt < NT; ++kt) {
    const int cur = kt & 1;
    if (kt + 1 < NT) asm volatile("s_waitcnt vmcnt(4)" ::: "memory");
    else             asm volatile("s_waitcnt vmcnt(0)" ::: "memory");
    __builtin_amdgcn_s_barrier();
    __builtin_amdgcn_sched_barrier(0);

    const char* Ab = (const char*)lds + cur*32768;
    const char* Bb = Ab + 16384;
    bf16x8 af[8], bf[4];
#pragma unroll
    for (int i = 0; i < 8; ++i) {
      int r = wm + i*16 + lr;
      af[i] = *(const bf16x8*)(Ab + r*64 + (kb ^ (((r >> 1) & 3) << 4)));
    }
#pragma unroll
    for (int i = 0; i < 4; ++i) {
      int r = wn + i*16 + lr;
      bf[i] = *(const bf16x8*)(Bb + r*64 + (kb ^ (((r >> 1) & 3) << 4)));
    }
    __builtin_amdgcn_s_setprio(1);
#pragma unroll
    for (int i = 0; i < 8; ++i)
#pragma unroll
      for (int j = 0; j < 4; ++j)
        acc[i][j] = __builtin_amdgcn_mfma_f32_16x16x32_bf16(af[i], bf[j], acc[i][j], 0, 0, 0);
    __builtin_amdgcn_s_setprio(0);
    __builtin_amdgcn_sched_barrier(0);
    __builtin_amdgcn_s_barrier();
    if (kt + 2 < NT) stage(kt + 2, cur);
  }

  const int orow = (lane >> 4) << 2;
  const int ocol = lane & 15;
#pragma unroll
  for (int mf = 0; mf < 8; ++mf)
#pragma unroll
    for (int nf = 0; nf < 4; ++nf) {
      long rbase = (long)(m0 + wm + mf*16 + orow);
      int col = n0 + wn + nf*16 + ocol;
      if (isQ) {
#pragma unroll
        for (int rr = 0; rr < 4; ++rr)
          qcat[(rbase + rr) * 3072L + col] = f2bf(acc[mf][nf][rr]);
      } else {
        int h = col >> 8, inner = col & 255;
        if (inner < 128) {
#pragma unroll
          for (int rr = 0; rr < 4; ++rr)
            kn[(rbase + rr) * 2048L + h*128 + inner] = f2bf(acc[mf][nf][rr]);
        } else {
          int bb = (int)(rbase >> 11);
          int t  = (int)(rbase & 2047);
          long vo = ((long)(bb*16 + h) * 128 + (inner - 128)) * 2048 + t;
          u16x4 o = { f2bf(acc[mf][nf][0]), f2bf(acc[mf][nf][1]),
                      f2bf(acc[mf][nf][2]), f2bf(acc[mf][nf][3]) };
          *(u16x4*)(Vt + vo) = o;
        }
      }
    }
}

// ---------------- fused dual RMSNorm (sums K-split partials) + k_rope extraction ----------------
// dkA/dkB: bf16 partial sums (K halves). Sums in fp32, normalizes, writes final to dkA.
__global__ __launch_bounds__(256) void rms_rope_dk(u16* __restrict__ dkA,
                                                   const u16* __restrict__ dkB,
                                                   const float* __restrict__ qnw,
                                                   const float* __restrict__ kvnw,
                                                   u16* __restrict__ Kr,
                                                   const float* __restrict__ cosb,
                                                   const float* __restrict__ sinb) {
  const long row = blockIdx.x;
  u16* xa = dkA + row * 2304;
  const u16* xb2 = dkB + row * 2304;
  const int i = threadIdx.x * 8;        // 256*8 = 2048, exact cover
  float sq = 0.f, sk = 0.f;
  u16x8 v1 = *(const u16x8*)(xa + i);
  u16x8 v2 = *(const u16x8*)(xb2 + i);
  float fv[8];
  {
    float s = 0.f;
#pragma unroll
    for (int e = 0; e < 8; ++e) { fv[e] = bf2f(v1[e]) + bf2f(v2[e]); s += fv[e]*fv[e]; }
    if (i < 1536) sq = s; else sk = s;
  }
#pragma unroll
  for (int off = 32; off > 0; off >>= 1) {
    sq += __shfl_down(sq, off);
    sk += __shfl_down(sk, off);
  }
  __shared__ float redq[4], redk[4];
  if ((threadIdx.x & 63) == 0) {
    redq[threadIdx.x >> 6] = sq;
    redk[threadIdx.x >> 6] = sk;
  }
  __syncthreads();
  float rq = rsqrtf((redq[0]+redq[1]+redq[2]+redq[3]) * (1.f/1536.f) + 1e-6f);
  float rk = rsqrtf((redk[0]+redk[1]+redk[2]+redk[3]) * (1.f/512.f) + 1e-6f);
  {
    float r = (i < 1536) ? rq : rk;
    const float* w = (i < 1536) ? (qnw + i) : (kvnw + (i - 1536));
    u16x8 o;
#pragma unroll
    for (int e = 0; e < 8; ++e) o[e] = f2bf(fv[e] * r * w[e]);
    *(u16x8*)(xa + i) = o;
  }
  if (threadIdx.x < 32) {
    const int t = (int)(row & (TT-1));
    int ii = threadIdx.x;
    float x0 = bf2f(xa[2048 + 2*ii])     + bf2f(xb2[2048 + 2*ii]);
    float x1 = bf2f(xa[2048 + 2*ii + 1]) + bf2f(xb2[2048 + 2*ii + 1]);
    float c = cosb[t*32 + ii], s = sinb[t*32 + ii];
    Kr[row*64 + 2*ii]     = f2bf(x0*c - x1*s);
    Kr[row*64 + 2*ii + 1] = f2bf(x0*s + x1*c);
  }
}

// ---------------- Flash attention v10: in-register Q-RoPE + static-max softmax + ones-MFMA ----------------
__global__ __launch_bounds__(512) void flash_attn10(const u16* __restrict__ qcat, // [ROWS,3072]
                                                    const u16* __restrict__ kn,   // [ROWS,2048]
                                                    const u16* __restrict__ kr,   // [ROWS,64]
                                                    const u16* __restrict__ Vt,   // [B*H,128,T]
                                                    const float* __restrict__ cosb,
                                                    const float* __restrict__ sinb,
                                                    u16* __restrict__ O) {        // [ROWS,2048]
  __shared__ __align__(16) u16 lds[36864];   // 73728 B
  const int bid = blockIdx.x;
  const int u = bid & 255, sl = bid >> 8;
  const int a = u >> 6;
  const int bh = u & 63;
  const int qt = sl ? a : (7 - a);
  const int b = bh >> 4, h = bh & 15;
  const int wid = threadIdx.x >> 6, lane = threadIdx.x & 63;
  const int q0 = qt*256 + wid*32;
  const long browq = (long)b * TT + q0;
  const long browk = (long)b * TT;
  const int l16 = lane >> 4;
  const int l8  = lane >> 3;
  const int lx16   = (lane & 15) * 16;
  const int lx8_16 = (lane & 7) * 16;
  const int co = l16 * 16;
  const float QSCE = 0.10411754661f;   // (1/sqrt(192)) * log2(e)

  bf16x8 qf[2][6];
#pragma unroll
  for (int f = 0; f < 2; ++f) {
    long row = browq + f*16 + (lane & 15);
#pragma unroll
    for (int ks = 0; ks < 4; ++ks)
      qf[f][ks] = *(const bf16x8*)(qcat + row * 3072 + h*128 + ks*32 + l16 * 8);
    const int t = (int)(row & (TT-1));
#pragma unroll
    for (int ks = 0; ks < 2; ++ks) {
      bf16x8 v = *(const bf16x8*)(qcat + row * 3072 + 2048 + h*64 + ks*32 + l16 * 8);
      const int ib = ks*16 + l16*4;
#pragma unroll
      for (int pp = 0; pp < 4; ++pp) {
        float x0 = (float)v[2*pp], x1 = (float)v[2*pp+1];
        float c = cosb[t*32 + ib + pp], s = sinb[t*32 + ib + pp];
        v[2*pp]   = (__bf16)((x0*c - x1*s) * QSCE);
        v[2*pp+1] = (__bf16)((x0*s + x1*c) * QSCE);
      }
      qf[f][4+ks] = v;
    }
  }

  bf16x8 vones;
#pragma unroll
  for (int e = 0; e < 8; ++e) vones[e] = (__bf16)1.0f;

  f32x4 oacc[2][8] = {};
  f32x4 lsum[2] = {};

  u16* pw = lds + 20480 + wid * 2048;

  const int nIter = 4*qt + 4;
  for (int it = 0; it < nIter; ++it) {
    const int s0 = it * 64;
#pragma unroll
    for (int j = 0; j < 2; ++j) {            // Kn
      int c = j*8 + wid;
      int r = c*4 + l16;
      int cb = lx16 ^ ((r & 7) << 4);
      const u16* src = (const u16*)((const char*)kn + (browk + s0 + r) * 4096 + h * 256 + cb);
      gload_lds16(src, lds + c*512);
    }
    {                                        // Kr
      int c = wid;
      int r = c*8 + l8;
      int cb = lx8_16 ^ ((r & 7) << 4);
      const u16* src = (const u16*)((const char*)kr + (browk + s0 + r) * 128 + cb);
      gload_lds16(src, lds + 8192 + c*512);
    }
#pragma unroll
    for (int j = 0; j < 2; ++j) {            // Vd
      int c = j*8 + wid;
      int d = c*8 + l8;
      int cb = lx8_16 ^ ((d & 7) << 4);
      const u16* src = (const u16*)((const char*)Vt + ((long)bh*128 + d) * (TT*2) + (long)s0*2 + cb);
      gload_lds16(src, lds + 12288 + c*512);
    }
    __syncthreads();

    const bool skip0 = s0 > q0 + 15;
    const bool skip1 = s0 > q0 + 31;
    if (!skip0 || !skip1) {
      __builtin_amdgcn_s_setprio(1);
      f32x4 sacc[2][4] = {};
#pragma unroll
      for (int nt = 0; nt < 4; ++nt) {
        const int r = nt*16 + (lane & 15);
        const int swz = (r & 7) << 4;
        bf16x8 kf[6];
#pragma unroll
        for (int ks = 0; ks < 4; ++ks)
          kf[ks] = *(const bf16x8*)((const char*)lds + r*256 + ((ks*64 + co) ^ swz));
#pragma unroll
        for (int ks = 0; ks < 2; ++ks)
          kf[4+ks] = *(const bf16x8*)((const char*)lds + 16384 + r*128 + ((ks*64 + co) ^ swz));
        if (!skip0) {
#pragma unroll
          for (int ks = 0; ks < 6; ++ks)
            sacc[0][nt] = __builtin_amdgcn_mfma_f32_16x16x32_bf16(qf[0][ks], kf[ks], sacc[0][nt], 0, 0, 0);
        }
        if (!skip1) {
#pragma unroll
          for (int ks = 0; ks < 6; ++ks)
            sacc[1][nt] = __builtin_amdgcn_mfma_f32_16x16x32_bf16(qf[1][ks], kf[ks], sacc[1][nt], 0, 0, 0);
        }
      }
      // static-max softmax: P = exp2(s - 16)
#pragma unroll
      for (int f = 0; f < 2; ++f) {
        const bool skipf = f ? skip1 : skip0;
        if (skipf) continue;
        const int qmin = q0 + f*16;
        const int qb = qmin + (l16 << 2);
        if (s0 + 63 > qmin) {
#pragma unroll
          for (int nt = 0; nt < 4; ++nt) {
            int sc = s0 + nt*16 + (lane & 15);
#pragma unroll
            for (int rr = 0; rr < 4; ++rr)
              if (sc > qb + rr) sacc[f][nt][rr] = -1e30f;
          }
        }
        const int lb2 = (lane & 15) * 2;
#pragma unroll
        for (int rr = 0; rr < 4; ++rr) {
          float p0 = exp2f(sacc[f][0][rr] - 16.f);
          float p1 = exp2f(sacc[f][1][rr] - 16.f);
          float p2 = exp2f(sacc[f][2][rr] - 16.f);
          float p3 = exp2f(sacc[f][3][rr] - 16.f);
          const int prow = f*16 + (l16 << 2) + rr;
          const int sw = (prow & 7) << 4;
          char* pb = (char*)pw + prow*128;
          *(u16*)(pb + ((     lb2) ^ sw)) = f2bf(p0);
          *(u16*)(pb + (( 32 + lb2) ^ sw)) = f2bf(p1);
          *(u16*)(pb + (( 64 + lb2) ^ sw)) = f2bf(p2);
          *(u16*)(pb + (( 96 + lb2) ^ sw)) = f2bf(p3);
        }
      }
      // PV + row-sum via ones-MFMA
#pragma unroll
      for (int ks = 0; ks < 2; ++ks) {
        const int cb = ks*64 + co;
        bf16x8 vf[8];
#pragma unroll
        for (int vt = 0; vt < 8; ++vt) {
          int row = vt*16 + (lane & 15);
          vf[vt] = *(const bf16x8*)((const char*)lds + 24576 + row*128 + (cb ^ ((row & 7) << 4)));
        }
#pragma unroll
        for (int f = 0; f < 2; ++f) {
          if (f ? skip1 : skip0) continue;
          int prow = f*16 + (lane & 15);
          bf16x8 pa = *(const bf16x8*)((const char*)pw + prow*128 + (cb ^ ((prow & 7) << 4)));
          lsum[f] = __builtin_amdgcn_mfma_f32_16x16x32_bf16(pa, vones, lsum[f], 0, 0, 0);
#pragma unroll
          for (int vt = 0; vt < 8; ++vt)
            oacc[f][vt] = __builtin_amdgcn_mfma_f32_16x16x32_bf16(pa, vf[vt], oacc[f][vt], 0, 0, 0);
        }
      }
      __builtin_amdgcn_s_setprio(0);
    }
    __syncthreads();
  }

#pragma unroll
  for (int f = 0; f < 2; ++f) {
    float inv[4];
#pragma unroll
    for (int rr = 0; rr < 4; ++rr) inv[rr] = 1.f / lsum[f][rr];
#pragma unroll
    for (int vt = 0; vt < 8; ++vt)
#pragma unroll
      for (int rr = 0; rr < 4; ++rr) {
        long row = browq + f*16 + (l16 << 2) + rr;
        int col = h*128 + vt*16 + (lane & 15);
        O[row * 2048 + col] = f2bf(oacc[f][vt][rr] * inv[rr]);
      }
  }
}

// ---------------- host ----------------
static inline long minl(long a, long b) { return a < b ? a : b; }

extern "C" void kernel_launch(void* const* d_in, const int* in_sizes, int n_in,
                              void* d_out, int out_size, void* d_ws, size_t ws_size,
                              hipStream_t stream) {
  const float* x    = (const float*)d_in[0];
  const float* fcos = (const float*)d_in[1];
  const float* fsin = (const float*)d_in[2];
  const float* qdw  = (const float*)d_in[4];
  const float* qnw  = (const float*)d_in[5];
  const float* qunw = (const float*)d_in[6];
  const float* qurw = (const float*)d_in[7];
  const float* kvdw = (const float*)d_in[8];
  const float* kvnw = (const float*)d_in[9];
  const float* kvuw = (const float*)d_in[10];
  const float* wow  = (const float*)d_in[11];
  float* out = (float*)d_out;

  char* p = (char*)d_ws;
  auto alloc = [&](size_t bytes) { char* r = p; p += (bytes + 255) & ~(size_t)255; return r; };

  u16* xb   = (u16*)alloc((size_t)ROWS*2048*2);   // x bf16; later Ob
  u16* wdc  = (u16*)alloc((size_t)2304*2048*2);
  u16* wuc  = (u16*)alloc((size_t)3072*1536*2);
  u16* wkvu = (u16*)alloc((size_t)4096*512*2);
  u16* wwo  = (u16*)alloc((size_t)2048*2048*2);
  u16* dk   = (u16*)alloc((size_t)ROWS*2304*2);
  u16* qcat = (u16*)alloc((size_t)ROWS*3072*2);
  u16* kn   = (u16*)alloc((size_t)ROWS*2048*2);
  u16* Vt   = (u16*)alloc((size_t)ROWS*2048*2);
  u16* kro  = (u16*)alloc((size_t)ROWS*64*2);

  u16* Ob  = xb;            // xb dead after down GEMM
  u16* dk2 = qcat;          // K-split partial; qcat written later by gemm_up (dk2 dead by then)

  const float QSC_E = 0.10411754661f;  // (1/sqrt(192)) * log2(e)

  cast_all<<<4096, 256, 0, stream>>>(x, qdw, kvdw, qunw, qurw, kvuw, wow,
                                     xb, wdc, wuc, wkvu, wwo, QSC_E);

  // down, K-split x2 (576 blocks): partials -> dk (kh0) + dk2 (kh1)
  gemm_down<<<dim3(9, 64), 512, 0, stream>>>(xb, wdc, dk, dk2);
  // fused dual rmsnorm (sums partials, in-place into dk) + k_rope extraction
  rms_rope_dk<<<ROWS, 256, 0, stream>>>(dk, dk2, qnw, kvnw, kro, fcos, fsin);
  // fused q_up + kv_up (896 blocks; q_up first = longest-first); overwrites dk2/qcat
  gemm_up<<<896, 512, 0, stream>>>(dk, wuc, wkvu, qcat, kn, Vt);
  flash_attn10<<<512, 512, 0, stream>>>(qcat, kn, kro, Vt, fcos, fsin, Ob);
  gemm256<0><<<dim3(8, 32), 512, 0, stream>>>(Ob, wwo, out, ROWS, 2048, 2048, 2048);
}